// Round 9
// baseline (671.214 us; speedup 1.0000x reference)
//
#include <hip/hip_runtime.h>
#include <hip/hip_bf16.h>
#include <math.h>

#define BB 4
#define SP 6272      // 28*28*8 spatial per batch
#define NSP 25088    // BB*SP
#define EPS 1e-5f

typedef unsigned short u16;
typedef __attribute__((ext_vector_type(8))) short v8s;   // 8 bf16 (4 VGPRs)
typedef __attribute__((ext_vector_type(4))) float v4f;   // MFMA accumulator

__device__ __forceinline__ u16 f2b(float f) {            // fp32 -> bf16 RNE
    unsigned u = __float_as_uint(f);
    return (u16)((u + 0x7fffu + ((u >> 16) & 1u)) >> 16);
}
__device__ __forceinline__ float b2f(u16 s) {
    return __uint_as_float(((unsigned)s) << 16);
}
__device__ __forceinline__ float b2f_lo(unsigned x) { return __uint_as_float(x << 16); }
__device__ __forceinline__ float b2f_hi(unsigned x) { return __uint_as_float(x & 0xffff0000u); }
__device__ __forceinline__ unsigned pk2(float a, float b) {   // v_cvt_pk_bf16_f32
    __hip_bfloat162 h = __float22bfloat162_rn(make_float2(a, b));
    unsigned u;
    __builtin_memcpy(&u, &h, 4);
    return u;
}

// ---------------- merged launch 1: prepack + ws zeroing + PP zeroing + conv1 ----------
// Block ranges: [0,4536) weight prepack; [4536,4544) zero ws[0..2048);
// [4544,7680) zero PP (deform partial buffer, 802816 uint4);
// [7680,7888) conv1 (writes per-block partial stats, reduced by conv2).
__global__ __launch_bounds__(256) void prepack_all(const float* __restrict__ c2w,
        const float* __restrict__ c3w, const float* __restrict__ ow,
        const float* __restrict__ dw, u16* __restrict__ wpk2,
        u16* __restrict__ wpk3, u16* __restrict__ wpko, u16* __restrict__ dwa,
        float* __restrict__ ws0, float* __restrict__ PP,
        const float* __restrict__ X, const float* __restrict__ Wt,
        const float* __restrict__ c1b, u16* __restrict__ Ybf,
        float* __restrict__ P1s, float* __restrict__ P1q)
{
    int bx = blockIdx.x;
    int tid = threadIdx.x;

    if (bx >= 7680) {                            // ---- conv1 blocks ----
        const int OT = 16;
        __shared__ float red[4][32];
        int c = bx - 7680;                       // [0,208)
        int xblk = c % 104;
        int o0 = (c / 104) * OT;
        int sblk = (xblk & 7) * 13 + (xblk >> 3);
        if (sblk >= 98) return;
        int t = tid;
        int s = sblk * 256 + t;
        int b = s / SP;
        int sp = s - b * SP;
        int d = sp / 224;
        int r = sp - d * 224;
        int h = r >> 3;
        int w = r & 7;

        float mdh[9]; int odh[9];
        #pragma unroll
        for (int i = 0; i < 3; i++) {
            int dd = d + i - 1;
            float md = ((unsigned)dd < 28u) ? 1.f : 0.f;
            int ddc = min(max(dd, 0), 27);
            #pragma unroll
            for (int j = 0; j < 3; j++) {
                int hh = h + j - 1;
                float mh = ((unsigned)hh < 28u) ? 1.f : 0.f;
                int hhc = min(max(hh, 0), 27);
                mdh[i * 3 + j] = md * mh;
                odh[i * 3 + j] = ddc * 224 + hhc * 8 + w;
            }
        }
        float mw0 = (w > 0) ? 1.f : 0.f;
        float mw2 = (w < 7) ? 1.f : 0.f;

        float acc[OT];
        #pragma unroll
        for (int oo = 0; oo < OT; oo++) acc[oo] = c1b[o0 + oo];

        const float* xc = X + (size_t)b * SP;
        #pragma unroll
        for (int t9 = 0; t9 < 9; t9++) {
            float x0 = xc[odh[t9]];
            float m = mdh[t9];
            float xm = __shfl_up(x0, 1, 64) * (m * mw0);
            float xz = x0 * m;
            float xp = __shfl_down(x0, 1, 64) * (m * mw2);
            #pragma unroll
            for (int oo = 0; oo < OT; oo++) {
                const float* wp = Wt + (size_t)(o0 + oo) * 27 + t9 * 3;
                acc[oo] = fmaf(xm, wp[0], acc[oo]);
                acc[oo] = fmaf(xz, wp[1], acc[oo]);
                acc[oo] = fmaf(xp, wp[2], acc[oo]);
            }
        }
        float sv[OT];
        #pragma unroll
        for (int oo = 0; oo < OT; oo++) sv[oo] = fmaxf(acc[oo], 0.f);

        unsigned pk[8];
        #pragma unroll
        for (int j = 0; j < 8; j++) pk[j] = pk2(sv[2 * j], sv[2 * j + 1]);
        u16* row = Ybf + (size_t)(b * SP + sp) * 32 + o0;
        *(uint4*)(row)     = make_uint4(pk[0], pk[1], pk[2], pk[3]);
        *(uint4*)(row + 8) = make_uint4(pk[4], pk[5], pk[6], pk[7]);

        int l = t & 63, wvv = t >> 6;
        #pragma unroll
        for (int oo = 0; oo < OT; oo++) {
            float ss = sv[oo], qv = ss * ss;
            #pragma unroll
            for (int m = 1; m < 64; m <<= 1) {
                ss += __shfl_xor(ss, m, 64);
                qv += __shfl_xor(qv, m, 64);
            }
            if (l == 0) { red[wvv][oo] = ss; red[wvv][16 + oo] = qv; }
        }
        __syncthreads();
        if (t < 32) {
            float tot = red[0][t] + red[1][t] + red[2][t] + red[3][t];
            if (t < 16) P1s[sblk * 32 + o0 + t] = tot;
            else        P1q[sblk * 32 + o0 + (t - 16)] = tot;
        }
        return;
    }

    if (bx >= 4544) {                            // ---- zero PP (deform partials) ----
        int i = (bx - 4544) * 256 + tid;         // [0, 802816) uint4
        ((uint4*)PP)[i] = make_uint4(0, 0, 0, 0);
        return;
    }

    if (bx >= 4536) {                            // 8 blocks: zero ws[0..2048)
        int i = (bx - 4536) * 256 + tid;
        if (i < 2048) ws0[i] = 0.f;
        return;
    }
    int idx = bx * 256 + tid;
    if (idx < 55296) {
        // wpk2[t][ot:4][q][r][j]  (CIN=32, NC=1)
        int i = idx;
        int j = i & 7, r = (i >> 3) & 15, q = (i >> 7) & 3;
        int ot = (i >> 9) & 3, t = i >> 11;
        int o = ot * 16 + r, c = q * 8 + j;
        wpk2[i] = f2b(c2w[((size_t)o * 32 + c) * 27 + t]);
    } else if (idx < 276480) {
        // wpk3[t][ot:8][ch:2][q][r][j]  (CIN=64)
        int i = idx - 55296;
        int j = i & 7, r = (i >> 3) & 15, q = (i >> 7) & 3;
        int ch = (i >> 9) & 1, ot = (i >> 10) & 7, t = i >> 13;
        int o = ot * 16 + r, c = ch * 32 + q * 8 + j;
        wpk3[i] = f2b(c3w[((size_t)o * 64 + c) * 27 + t]);
    } else if (idx < 718848) {
        // wpko[t][ot:8][ch:4][q][r][j]  (CIN=128, o>=81 zero)
        int i = idx - 276480;
        int j = i & 7, r = (i >> 3) & 15, q = (i >> 7) & 3;
        int ch = (i >> 9) & 3, ot = (i >> 11) & 7, t = i >> 14;
        int o = ot * 16 + r, c = ch * 32 + q * 8 + j;
        wpko[i] = f2b((o < 81) ? ow[((size_t)o * 128 + c) * 27 + t] : 0.f);
    } else {
        int i = idx - 718848;   // dwa[n][ot][kc][q][r][j]
        int j = i & 7, r = (i >> 3) & 15, q = (i >> 7) & 3;
        int kc = (i >> 9) & 3, ot = (i >> 11) & 7, n = i >> 14;
        int o = ot * 16 + r, c = kc * 32 + q * 8 + j;
        dwa[i] = f2b(dw[((size_t)o * 128 + c) * 27 + n]);
    }
}

// ---------------- MFMA implicit-GEMM conv 3x3x3 (CIN>=32, bf16) ----------------
// BNIN:   apply per-channel affine (from stats) during LDS staging.
// PARTIN: stats come as 98 per-block partials (conv1) -> strided reduce.
// WIDE:   128 outputs in ONE block; wave owns o-tiles wv, wv+4 x 2 d-slices.
// OFFOUT: merged offsets conv; wave = (d-slice, o-tile trio), o in [0,96).
// Weights read in fragment layout (see prepack_all; R20 fix: -120us).
template<int CIN, int OPAD, bool OFFOUT, bool BNIN, bool WIDE, bool PARTIN>
__global__ __launch_bounds__(256) __attribute__((amdgpu_waves_per_eu(1, 4)))
void conv_mfma(const u16* __restrict__ X, const u16* __restrict__ Wpk,
               const float* __restrict__ bias, u16* __restrict__ Ybf,
               float* __restrict__ offs, float* __restrict__ s_sum,
               float* __restrict__ s_sq, const float* __restrict__ in_sum,
               const float* __restrict__ in_sq, const float* __restrict__ in_g,
               const float* __restrict__ in_b)
{
    const int HS = CIN + 8;                 // LDS stride per position (bf16 units)
    const int NOT = OPAD / 16;              // o-tiles in fragment layout
    const int NC = CIN / 32;                // c-chunks in fragment layout
    __shared__ u16 xs[160 * HS];            // [dz 0..3][hz 0..3][wz 0..9][c]
    __shared__ float scin[BNIN ? CIN : 1], shin[BNIN ? CIN : 1];

    int tid = threadIdx.x;
    int fid = blockIdx.x;                   // [0,784) = 8 XCDs x 98
    int g = (fid & 7) * 98 + (fid >> 3);
    int b = g / 196;
    int rem = g - b * 196;
    int d0 = (rem / 14) * 2, h0 = (rem % 14) * 2;

    if (BNIN) {
        if (PARTIN) {
            __shared__ float ps[8][32], pq[8][32];
            int ch = tid & 31, ck = tid >> 5;
            float s = 0.f, qq = 0.f;
            for (int k = ck; k < 98; k += 8) {
                s  += in_sum[k * 32 + ch];
                qq += in_sq[k * 32 + ch];
            }
            ps[ck][ch] = s; pq[ck][ch] = qq;
            __syncthreads();
            if (tid < CIN) {
                float m = 0.f, vq = 0.f;
                #pragma unroll
                for (int k2 = 0; k2 < 8; k2++) { m += ps[k2][tid]; vq += pq[k2][tid]; }
                m *= (1.f / NSP);
                vq = vq * (1.f / NSP) - m * m;
                float sc = in_g[tid] * rsqrtf(vq + EPS);
                scin[tid] = sc;
                shin[tid] = in_b[tid] - m * sc;
            }
            __syncthreads();
        } else {
            if (tid < CIN) {
                float m = in_sum[tid] * (1.f / NSP);
                float v = in_sq[tid] * (1.f / NSP) - m * m;
                float sc = in_g[tid] * rsqrtf(v + EPS);
                scin[tid] = sc;
                shin[tid] = in_b[tid] - m * sc;
            }
            __syncthreads();
        }
    }

    const int NCH = CIN / 8;
    for (int idx = tid; idx < 160 * NCH; idx += 256) {
        int pos = idx / NCH, ch = idx - pos * NCH;
        int dz = pos / 40, r2 = pos - dz * 40;
        int hz = r2 / 10, wz = r2 - hz * 10;
        int dd = d0 + dz - 1, hh = h0 + hz - 1, ww = wz - 1;
        uint4 val = make_uint4(0, 0, 0, 0);
        if ((unsigned)dd < 28u && (unsigned)hh < 28u && (unsigned)ww < 8u) {
            val = *(const uint4*)(X + ((size_t)(b * SP + dd * 224 + hh * 8 + ww) * CIN + ch * 8));
            if (BNIN) {
                int cb = ch * 8;
                float f0 = b2f_lo(val.x) * scin[cb]     + shin[cb];
                float f1 = b2f_hi(val.x) * scin[cb + 1] + shin[cb + 1];
                float f2 = b2f_lo(val.y) * scin[cb + 2] + shin[cb + 2];
                float f3 = b2f_hi(val.y) * scin[cb + 3] + shin[cb + 3];
                float f4 = b2f_lo(val.z) * scin[cb + 4] + shin[cb + 4];
                float f5 = b2f_hi(val.z) * scin[cb + 5] + shin[cb + 5];
                float f6 = b2f_lo(val.w) * scin[cb + 6] + shin[cb + 6];
                float f7 = b2f_hi(val.w) * scin[cb + 7] + shin[cb + 7];
                val.x = pk2(f0, f1); val.y = pk2(f2, f3);
                val.z = pk2(f4, f5); val.w = pk2(f6, f7);
            }
        }
        *(uint4*)(xs + pos * HS + ch * 8) = val;
    }
    __syncthreads();

    int l = tid & 63, wv = tid >> 6;
    int q = l >> 4, r = l & 15;
    int hl = r >> 3, wl = r & 7;

    if (OFFOUT) {
        // merged offsets conv: wave = (d-slice dl, o-tile trio ot0..ot0+2)
        int dl = wv >> 1;
        int ot0 = (wv & 1) * 3;
        const u16* ap = xs + ((4 + hl + 1) * 10 + wl + 1) * HS + 8 * q + dl * 40 * HS;
        v4f acc[3];
        acc[0] = (v4f){0.f,0.f,0.f,0.f};
        acc[1] = (v4f){0.f,0.f,0.f,0.f};
        acc[2] = (v4f){0.f,0.f,0.f,0.f};
        #pragma unroll
        for (int t = 0; t < 27; t++) {
            const int koff = ((t / 9) - 1) * 40 + (((t / 3) % 3) - 1) * 10 + (t % 3) - 1;
            const u16* wt = Wpk + ((size_t)(t * NOT + ot0) * NC << 9) + l * 8;
            #pragma unroll
            for (int ch = 0; ch < NC; ch++) {
                v8s a0 = *(const v8s*)(ap + koff * HS + ch * 32);
                v8s b0 = *(const v8s*)(wt + ch * 512);
                v8s b1 = *(const v8s*)(wt + (NC + ch) * 512);
                v8s b2 = *(const v8s*)(wt + (2 * NC + ch) * 512);
                acc[0] = __builtin_amdgcn_mfma_f32_16x16x32_bf16(a0, b0, acc[0], 0, 0, 0);
                acc[1] = __builtin_amdgcn_mfma_f32_16x16x32_bf16(a0, b1, acc[1], 0, 0, 0);
                acc[2] = __builtin_amdgcn_mfma_f32_16x16x32_bf16(a0, b2, acc[2], 0, 0, 0);
            }
        }
        int o0 = ot0 * 16 + r;
        #pragma unroll
        for (int j = 0; j < 3; j++) {
            int o = o0 + 16 * j;
            if (o < 81) {
                float bo = bias[o];
                #pragma unroll
                for (int rg = 0; rg < 4; rg++) {
                    int rowl = q * 4 + rg;
                    int sp = (d0 + dl) * 224 + (h0 + (rowl >> 3)) * 8 + (rowl & 7);
                    offs[((size_t)(b * 81 + o)) * SP + sp] = acc[j][rg] + bo;
                }
            }
        }
        return;
    }

    const u16* a0p = xs + ((4 + hl + 1) * 10 + wl + 1) * HS + 8 * q;  // dl=0
    const u16* a1p = a0p + 40 * HS;                                   // dl=1

    if (WIDE) {
        // 128 outputs per block: wave owns o-tiles wv and wv+4 (o, o+64)
        v4f acc[2][2];                       // [oti][dl]
        acc[0][0] = (v4f){0.f,0.f,0.f,0.f}; acc[0][1] = (v4f){0.f,0.f,0.f,0.f};
        acc[1][0] = (v4f){0.f,0.f,0.f,0.f}; acc[1][1] = (v4f){0.f,0.f,0.f,0.f};
        #pragma unroll
        for (int t = 0; t < 27; t++) {
            const int koff = ((t / 9) - 1) * 40 + (((t / 3) % 3) - 1) * 10 + (t % 3) - 1;
            const u16* wt  = Wpk + ((size_t)(t * NOT + wv) * NC << 9) + l * 8;
            const u16* wt2 = wt + (size_t)4 * NC * 512;      // ot = wv+4
            #pragma unroll
            for (int ch = 0; ch < NC; ch++) {
                v8s a0 = *(const v8s*)(a0p + koff * HS + ch * 32);
                v8s a1 = *(const v8s*)(a1p + koff * HS + ch * 32);
                v8s b0 = *(const v8s*)(wt + ch * 512);
                v8s b1 = *(const v8s*)(wt2 + ch * 512);
                acc[0][0] = __builtin_amdgcn_mfma_f32_16x16x32_bf16(a0, b0, acc[0][0], 0, 0, 0);
                acc[0][1] = __builtin_amdgcn_mfma_f32_16x16x32_bf16(a1, b0, acc[0][1], 0, 0, 0);
                acc[1][0] = __builtin_amdgcn_mfma_f32_16x16x32_bf16(a0, b1, acc[1][0], 0, 0, 0);
                acc[1][1] = __builtin_amdgcn_mfma_f32_16x16x32_bf16(a1, b1, acc[1][1], 0, 0, 0);
            }
        }
        #pragma unroll
        for (int oti = 0; oti < 2; oti++) {
            int o_base = wv * 16 + oti * 64;
            int oo = o_base + r;
            float bo = bias[oo];
            float rs = 0.f, rq = 0.f;
            #pragma unroll
            for (int s2 = 0; s2 < 2; s2++) {
                v4f A = acc[oti][s2];
                #pragma unroll
                for (int rg = 0; rg < 4; rg++) {
                    int rowl = q * 4 + rg;
                    int sp = (d0 + s2) * 224 + (h0 + (rowl >> 3)) * 8 + (rowl & 7);
                    float v = fmaxf(A[rg] + bo, 0.f);
                    Ybf[(size_t)(b * SP + sp) * OPAD + oo] = f2b(v);
                    rs += v; rq += v * v;
                }
            }
            rs += __shfl_xor(rs, 16, 64); rs += __shfl_xor(rs, 32, 64);
            rq += __shfl_xor(rq, 16, 64); rq += __shfl_xor(rq, 32, 64);
            if (l < 16) { atomicAdd(&s_sum[o_base + l], rs); atomicAdd(&s_sq[o_base + l], rq); }
        }
        return;
    }

    int o_base = blockIdx.y * 64 + wv * 16;
    int o = o_base + r;
    int otg = o_base >> 4;                   // fragment o-tile index

    v4f acc0 = {0.f, 0.f, 0.f, 0.f}, acc1 = {0.f, 0.f, 0.f, 0.f};
    #pragma unroll
    for (int t = 0; t < 27; t++) {
        const int koff = ((t / 9) - 1) * 40 + (((t / 3) % 3) - 1) * 10 + (t % 3) - 1;
        const u16* wt = Wpk + ((size_t)(t * NOT + otg) * NC << 9) + l * 8;
        #pragma unroll
        for (int ch = 0; ch < NC; ch++) {
            v8s a0 = *(const v8s*)(a0p + koff * HS + ch * 32);
            v8s a1 = *(const v8s*)(a1p + koff * HS + ch * 32);
            v8s bf = *(const v8s*)(wt + ch * 512);
            acc0 = __builtin_amdgcn_mfma_f32_16x16x32_bf16(a0, bf, acc0, 0, 0, 0);
            acc1 = __builtin_amdgcn_mfma_f32_16x16x32_bf16(a1, bf, acc1, 0, 0, 0);
        }
    }

    {
        float bo = bias[o];
        float rs = 0.f, rq = 0.f;
        #pragma unroll
        for (int s2 = 0; s2 < 2; s2++) {
            v4f A = s2 ? acc1 : acc0;
            #pragma unroll
            for (int rg = 0; rg < 4; rg++) {
                int rowl = q * 4 + rg;
                int sp = (d0 + s2) * 224 + (h0 + (rowl >> 3)) * 8 + (rowl & 7);
                float v = fmaxf(A[rg] + bo, 0.f);
                Ybf[(size_t)(b * SP + sp) * OPAD + o] = f2b(v);
                rs += v; rq += v * v;
            }
        }
        rs += __shfl_xor(rs, 16, 64); rs += __shfl_xor(rs, 32, 64);
        rq += __shfl_xor(rq, 16, 64); rq += __shfl_xor(rq, 32, 64);
        if (l < 16) { atomicAdd(&s_sum[o_base + l], rs); atomicAdd(&s_sq[o_base + l], rq); }
    }
}

// ---------------- BN apply on channel-minor bf16, vectorized uint4/lane (in-place OK) --
template<int C>
__global__ __launch_bounds__(256) void bn_bf(const u16* __restrict__ Y,
        const float* __restrict__ s_sum, const float* __restrict__ s_sq,
        const float* __restrict__ g, const float* __restrict__ bb,
        u16* __restrict__ Xo)
{
    __shared__ float sc_s[C], sh_s[C];
    int t = threadIdx.x;
    if (t < C) {
        float m  = s_sum[t] * (1.f / NSP);
        float v  = s_sq[t] * (1.f / NSP) - m * m;
        float sc = g[t] * rsqrtf(v + EPS);
        sc_s[t] = sc;
        sh_s[t] = bb[t] - m * sc;
    }
    __syncthreads();
    int idx = blockIdx.x * 256 + t;              // uint4 index, [0, NSP*C/8)
    uint4 v = ((const uint4*)Y)[idx];
    int cb = (idx & (C / 8 - 1)) * 8;
    float f0 = b2f_lo(v.x) * sc_s[cb]     + sh_s[cb];
    float f1 = b2f_hi(v.x) * sc_s[cb + 1] + sh_s[cb + 1];
    float f2 = b2f_lo(v.y) * sc_s[cb + 2] + sh_s[cb + 2];
    float f3 = b2f_hi(v.y) * sc_s[cb + 3] + sh_s[cb + 3];
    float f4 = b2f_lo(v.z) * sc_s[cb + 4] + sh_s[cb + 4];
    float f5 = b2f_hi(v.z) * sc_s[cb + 5] + sh_s[cb + 5];
    float f6 = b2f_lo(v.w) * sc_s[cb + 6] + sh_s[cb + 6];
    float f7 = b2f_hi(v.w) * sc_s[cb + 7] + sh_s[cb + 7];
    uint4 pk;
    pk.x = pk2(f0, f1); pk.y = pk2(f2, f3);
    pk.z = pk2(f4, f5); pk.w = pk2(f6, f7);
    ((uint4*)Xo)[idx] = pk;
}

// ---------------- deformable conv (MFMA) -- R24: tap-split across 2 blocks ----------
// R12 per-tap structure (geometry/sample/MFMA verbatim); each tile's 27 taps split
// [0,14)/[14,27) across paired blocks (bid, bid+800). Grid 1600, LDS ~22KB ->
// ~6 blocks/CU resident (was grid-limited at ~3: Occupancy 25%). Halves atomicAdd
// fp32 partials into zeroed PP[tile][128*32] (2-way add = order-independent);
// second finisher per tile (fence+counter, R18-proven) runs the epilogue.
__global__ __launch_bounds__(256) __attribute__((amdgpu_waves_per_eu(1, 4)))
void deform_pool(const u16* __restrict__ Ht, const float* __restrict__ OFF,
                 const u16* __restrict__ Wa, const float* __restrict__ db,
                 float* __restrict__ pooledraw, float* __restrict__ sumsq4,
                 float* __restrict__ PP, unsigned* __restrict__ cnt)
{
    __shared__ float offs_lds[81 * 32];     // [ch][p]
    __shared__ int ig_s[32][8][2];          // [p][corner][{idx, g bits}]
    __shared__ u16 Vb[32][136];             // B operand [p][c] bf16, row pad +8
    __shared__ float reds[128], redq[128];
    __shared__ unsigned done_s;

    int bid = blockIdx.x;          // [0,1600)
    int half = bid >= 800;
    int fid = half ? bid - 800 : bid;
    int xcd = fid & 7;
    int local = fid >> 3;          // [0,100)
    if (local >= 98) return;
    int dense = xcd * 98 + local;  // [0,784)
    int b = xcd >> 1;
    int d = (xcd & 1) * 14 + local / 7;
    int h0 = (local % 7) * 4;

    int t = threadIdx.x;
    if (t < 128) { reds[t] = 0.f; redq[t] = 0.f; }

    int gp = t >> 3, gcr = t & 7;                  // geometry role
    int glh = gp >> 3, gw = gp & 7, gh = h0 + glh;
    int co = t & 15, pg = t >> 4;                  // sample role: c-oct, p-pair
    int l = t & 63, wv = t >> 6;                   // MFMA role
    int q = l >> 4, r = l & 15;

    v4f acc[2][2];                                 // [o-tile][p-tile]
    acc[0][0] = (v4f){0.f,0.f,0.f,0.f}; acc[0][1] = (v4f){0.f,0.f,0.f,0.f};
    acc[1][0] = (v4f){0.f,0.f,0.f,0.f}; acc[1][1] = (v4f){0.f,0.f,0.f,0.f};

    const u16* hb = Ht + (size_t)b * SP * 128;

    // ---- stage offsets for this block's 32 positions (coalesced, once) ----
    for (int i = t; i < 2592; i += 256) {
        int ch = i >> 5, p = i & 31;
        offs_lds[i] = OFF[(size_t)b * 81 * SP + (size_t)ch * SP
                          + d * 224 + (h0 + (p >> 3)) * 8 + (p & 7)];
    }

    int n_lo = half ? 14 : 0;
    int n_hi = half ? 27 : 14;
    for (int n = n_lo; n < n_hi; n++) {
        __syncthreads();   // prev MFMA done reading Vb (and offs_lds ready, first iter)
        {   // ---- geometry for (n, gp, gcr) ----
            int kd = n / 9 - 1, kh = (n / 3) % 3 - 1, kw = n % 3 - 1;
            float od  = offs_lds[n * 32 + gp];
            float oh  = offs_lds[(27 + n) * 32 + gp];
            float owv = offs_lds[(54 + n) * 32 + gp];
            float pd = fminf(fmaxf((float)(d + 1 + kd) + od, 0.f), 29.f);
            float ph = fminf(fmaxf((float)(gh + 1 + kh) + oh, 0.f), 29.f);
            float pw = fminf(fmaxf((float)(gw + 1 + kw) + owv, 0.f), 9.f);
            float qd = fminf(floorf(pd), 28.f);
            float qh = fminf(floorf(ph), 28.f);
            float qw = fminf(floorf(pw), 8.f);
            float td = fminf(pd - qd, 1.f);
            float th = fminf(ph - qh, 1.f);
            float tw = fminf(pw - qw, 1.f);
            int iqd = (int)qd - 1, iqh = (int)qh - 1, iqw = (int)qw - 1;
            int i = gcr >> 2, j = (gcr >> 1) & 1, k = gcr & 1;
            int du = iqd + i, hu = iqh + j, wu = iqw + k;
            bool val = (unsigned)du < 28u && (unsigned)hu < 28u && (unsigned)wu < 8u;
            float gg = (i ? td : 1.f - td) * (j ? th : 1.f - th) * (k ? tw : 1.f - tw);
            ig_s[gp][gcr][0] = val ? (du * 224 + hu * 8 + wu) : 0;
            ig_s[gp][gcr][1] = __float_as_int(val ? gg : 0.f);
        }
        __syncthreads();
        // ---- phase 2: V[p][c] trilinear sample, 8 channels/load ----
        #pragma unroll
        for (int pp = 0; pp < 2; pp++) {
            int p = pg * 2 + pp;
            float va[8] = {0.f,0.f,0.f,0.f,0.f,0.f,0.f,0.f};
            #pragma unroll
            for (int cr = 0; cr < 8; cr++) {
                int2 pr = *(const int2*)&ig_s[p][cr][0];
                float gg = __int_as_float(pr.y);
                uint4 xv = *(const uint4*)(hb + (size_t)pr.x * 128 + co * 8);
                va[0] = fmaf(gg, b2f_lo(xv.x), va[0]);
                va[1] = fmaf(gg, b2f_hi(xv.x), va[1]);
                va[2] = fmaf(gg, b2f_lo(xv.y), va[2]);
                va[3] = fmaf(gg, b2f_hi(xv.y), va[3]);
                va[4] = fmaf(gg, b2f_lo(xv.z), va[4]);
                va[5] = fmaf(gg, b2f_hi(xv.z), va[5]);
                va[6] = fmaf(gg, b2f_lo(xv.w), va[6]);
                va[7] = fmaf(gg, b2f_hi(xv.w), va[7]);
            }
            uint4 pk;
            pk.x = pk2(va[0], va[1]); pk.y = pk2(va[2], va[3]);
            pk.z = pk2(va[4], va[5]); pk.w = pk2(va[6], va[7]);
            *(uint4*)&Vb[p][co * 8] = pk;
        }
        __syncthreads();
        // ---- phase 3: out[o][p] += W[o][c] * V[c][p] via MFMA ----
        const u16* wn = Wa + (size_t)n * 16384;
        #pragma unroll
        for (int oti = 0; oti < 2; oti++) {
            int ot = wv * 2 + oti;
            #pragma unroll
            for (int kc = 0; kc < 4; kc++) {
                v8s af = *(const v8s*)(wn + ((((ot * 4 + kc) * 4 + q) * 16 + r) * 8));
                v8s bf0 = *(const v8s*)&Vb[r][kc * 32 + q * 8];
                v8s bf1 = *(const v8s*)&Vb[16 + r][kc * 32 + q * 8];
                acc[oti][0] = __builtin_amdgcn_mfma_f32_16x16x32_bf16(af, bf0, acc[oti][0], 0, 0, 0);
                acc[oti][1] = __builtin_amdgcn_mfma_f32_16x16x32_bf16(af, bf1, acc[oti][1], 0, 0, 0);
            }
        }
    }

    // ---- publish partial acc (fp32 atomic add into zeroed PP) ----
    float* pp = PP + (size_t)dense * 4096 + t * 16;
    #pragma unroll
    for (int oti = 0; oti < 2; oti++)
        #pragma unroll
        for (int pt = 0; pt < 2; pt++)
            #pragma unroll
            for (int rg = 0; rg < 4; rg++)
                atomicAdd(&pp[(oti * 2 + pt) * 4 + rg], acc[oti][pt][rg]);
    __syncthreads();
    if (t == 0) {
        __threadfence();
        done_s = atomicAdd(&cnt[dense], 1u);
    }
    __syncthreads();
    if (done_s != 1u) return;      // first finisher exits; second runs epilogue

    __threadfence();               // acquire partner's adds
    float4 t00 = *(const float4*)(pp + 0);
    float4 t01 = *(const float4*)(pp + 4);
    float4 t10 = *(const float4*)(pp + 8);
    float4 t11 = *(const float4*)(pp + 12);
    float tt[2][2][4] = {
        {{t00.x, t00.y, t00.z, t00.w}, {t01.x, t01.y, t01.z, t01.w}},
        {{t10.x, t10.y, t10.z, t10.w}, {t11.x, t11.y, t11.z, t11.w}}
    };

    // ---- epilogue: bias + relu + pooled sum / sumsq ----
    #pragma unroll
    for (int oti = 0; oti < 2; oti++) {
        #pragma unroll
        for (int rg = 0; rg < 4; rg++) {
            int o = (wv * 2 + oti) * 16 + q * 4 + rg;
            float bo = db[o];
            float v0 = fmaxf(tt[oti][0][rg] + bo, 0.f);
            float v1 = fmaxf(tt[oti][1][rg] + bo, 0.f);
            float s = v0 + v1, qq = v0 * v0 + v1 * v1;
            s += __shfl_xor(s, 1, 64);  qq += __shfl_xor(qq, 1, 64);
            s += __shfl_xor(s, 2, 64);  qq += __shfl_xor(qq, 2, 64);
            s += __shfl_xor(s, 4, 64);  qq += __shfl_xor(qq, 4, 64);
            s += __shfl_xor(s, 8, 64);  qq += __shfl_xor(qq, 8, 64);
            if (r == 0) { atomicAdd(&reds[o], s); atomicAdd(&redq[o], qq); }
        }
    }
    __syncthreads();
    if (t < 128) {
        atomicAdd(&pooledraw[b * 128 + t], reds[t]);
        atomicAdd(&sumsq4[t], redq[t]);
    }
}

// ---------------- tail kernel: BN4+pool+FC+log_softmax (offsets already in d_out) ----
__global__ __launch_bounds__(256) void final_head_emit(const float* __restrict__ pooledraw,
        const float* __restrict__ sumsq4, const float* __restrict__ g4,
        const float* __restrict__ b4, const float* __restrict__ fcw,
        const float* __restrict__ fcb, float* __restrict__ out)
{
    int t = threadIdx.x;
    __shared__ float pooled_s[4][128];
    __shared__ float logits[4][10];
    if (t < 128) {
        float s0 = pooledraw[t], s1 = pooledraw[128 + t];
        float s2 = pooledraw[256 + t], s3 = pooledraw[384 + t];
        float tot = s0 + s1 + s2 + s3;
        float m  = tot * (1.f / NSP);
        float v  = sumsq4[t] * (1.f / NSP) - m * m;
        float sc = g4[t] * rsqrtf(v + EPS);
        float sh = b4[t] - m * sc;
        pooled_s[0][t] = s0 * (1.f / SP) * sc + sh;
        pooled_s[1][t] = s1 * (1.f / SP) * sc + sh;
        pooled_s[2][t] = s2 * (1.f / SP) * sc + sh;
        pooled_s[3][t] = s3 * (1.f / SP) * sc + sh;
    }
    __syncthreads();
    if (t < 40) {
        int b = t / 10, j = t % 10;
        float l = fcb[j];
        for (int c = 0; c < 128; c++) l = fmaf(pooled_s[b][c], fcw[j * 128 + c], l);
        logits[b][j] = l;
    }
    __syncthreads();
    if (t < 4) {
        float mx = -1e30f;
        for (int j = 0; j < 10; j++) mx = fmaxf(mx, logits[t][j]);
        float se = 0.f;
        for (int j = 0; j < 10; j++) se += expf(logits[t][j] - mx);
        float lse = mx + logf(se);
        for (int j = 0; j < 10; j++) out[t * 10 + j] = logits[t][j] - lse;
    }
}

extern "C" void kernel_launch(void* const* d_in, const int* in_sizes, int n_in,
                              void* d_out, int out_size, void* d_ws, size_t ws_size,
                              hipStream_t stream)
{
    (void)in_sizes; (void)n_in; (void)out_size; (void)ws_size;
    const float* x   = (const float*)d_in[0];
    const float* c1w = (const float*)d_in[1];
    const float* c1b = (const float*)d_in[2];
    const float* g1  = (const float*)d_in[3];
    const float* b1  = (const float*)d_in[4];
    const float* c2w = (const float*)d_in[5];
    const float* c2b = (const float*)d_in[6];
    const float* g2  = (const float*)d_in[7];
    const float* b2  = (const float*)d_in[8];
    const float* c3w = (const float*)d_in[9];
    const float* c3b = (const float*)d_in[10];
    const float* g3  = (const float*)d_in[11];
    const float* b3  = (const float*)d_in[12];
    const float* ow  = (const float*)d_in[13];
    const float* ob  = (const float*)d_in[14];
    const float* dw  = (const float*)d_in[15];
    const float* db  = (const float*)d_in[16];
    const float* g4  = (const float*)d_in[17];
    const float* b4  = (const float*)d_in[18];
    const float* fcw = (const float*)d_in[19];
    const float* fcb = (const float*)d_in[20];

    float* ws = (float*)d_ws;
    float* S2 = ws + 64,  *Q2 = ws + 128;
    float* S3 = ws + 192, *Q3 = ws + 320;
    float* PO = ws + 448;            // 4*128
    float* Q4 = ws + 960;            // 128
    unsigned* cnt = (unsigned*)(ws + 1152);  // 784 tile counters (zeroed by ws0)
    float* P1s = ws + 4096;          // 98*32 conv1 partial sums
    float* P1q = ws + 7232;          // 98*32 conv1 partial sumsq
    u16* y1bf = (u16*)(ws + 16384);        // NSP*32
    u16* y2bf = y1bf + 802816;             // NSP*64
    u16* y3bf = y2bf + 1605632;            // NSP*128; BN3 applied IN PLACE (L4b)
    u16* wpk2 = y3bf + 3211264;            // 27*64*32
    u16* wpk3 = wpk2 + 55296;              // 27*128*64
    u16* wpko = wpk3 + 221184;             // 27*128*128 (o>=81 zero)
    u16* dwa  = wpko + 442368;             // 27*128*128 A-frag layout bf16
    float* PP = (float*)(dwa + 442368);    // 784*4096 deform partial accs (12.85MB)

    float* outf = (float*)d_out;
    float* offp = outf + 40;               // offsets written DIRECTLY to d_out

    // L1: prepack + ws-zero + PP-zero + conv1 (independent, overlapped)
    prepack_all<<<7888, 256, 0, stream>>>(c2w, c3w, ow, dw, wpk2, wpk3, wpko, dwa,
                                          ws, PP, x, c1w, c1b, y1bf, P1s, P1q);

    // L2: conv2 (BN1 from conv1 partials)
    conv_mfma<32, 64, false, true, false, true><<<784, 256, 0, stream>>>(
        y1bf, wpk2, c2b, y2bf, nullptr, S2, Q2, P1s, P1q, g1, b1);

    // L3: conv3 WIDE (BN2 from atomics)
    conv_mfma<64, 128, false, true, true, false><<<784, 256, 0, stream>>>(
        y2bf, wpk3, c3b, y3bf, nullptr, S3, Q3, S2, Q2, g2, b2);

    // L4a: offsets conv (reads RAW y3bf, BN3 applied during staging)
    conv_mfma<128, 128, true, true, false, false><<<784, 256, 0, stream>>>(
        y3bf, wpko, ob, nullptr, offp, nullptr, nullptr, S3, Q3, g3, b3);

    // L4b: BN3 in place on y3bf (deform input)
    bn_bf<128><<<1568, 256, 0, stream>>>(y3bf, S3, Q3, g3, b3, y3bf);

    // L5: deform, tap-split 2x (grid 1600)
    deform_pool<<<1600, 256, 0, stream>>>(y3bf, offp, dwa, db, PO, Q4, PP, cnt);

    // L6: head
    final_head_emit<<<1, 256, 0, stream>>>(PO, Q4, g4, b4, fcw, fcb, outf);
}

// Round 10
// 364.714 us; speedup vs baseline: 1.8404x; 1.8404x over previous
//
#include <hip/hip_runtime.h>
#include <hip/hip_bf16.h>
#include <math.h>

#define BB 4
#define SP 6272      // 28*28*8 spatial per batch
#define NSP 25088    // BB*SP
#define EPS 1e-5f

typedef unsigned short u16;
typedef __attribute__((ext_vector_type(8))) short v8s;   // 8 bf16 (4 VGPRs)
typedef __attribute__((ext_vector_type(4))) float v4f;   // MFMA accumulator

__device__ __forceinline__ u16 f2b(float f) {            // fp32 -> bf16 RNE
    unsigned u = __float_as_uint(f);
    return (u16)((u + 0x7fffu + ((u >> 16) & 1u)) >> 16);
}
__device__ __forceinline__ float b2f(u16 s) {
    return __uint_as_float(((unsigned)s) << 16);
}
__device__ __forceinline__ float b2f_lo(unsigned x) { return __uint_as_float(x << 16); }
__device__ __forceinline__ float b2f_hi(unsigned x) { return __uint_as_float(x & 0xffff0000u); }
__device__ __forceinline__ unsigned pk2(float a, float b) {   // v_cvt_pk_bf16_f32
    __hip_bfloat162 h = __float22bfloat162_rn(make_float2(a, b));
    unsigned u;
    __builtin_memcpy(&u, &h, 4);
    return u;
}

// ---------------- merged launch 1: weight prepack + ws zeroing + conv1 ----------------
// conv1 (1->32, shuffle form) rides as blocks [4544, 4752); data-independent of the
// prepack work, so it overlaps. conv1 writes PER-BLOCK partial stats (P1s/P1q,
// no atomics -> no same-launch zero-init dependency); conv2's preamble reduces them.
// Weights are packed in FRAGMENT layout [t][ot][ch][q][r][j] (lane l reads 16B at
// base + l*8): one coalesced 1KB request per B-load (R20 fix: -120us).
__global__ __launch_bounds__(256) void prepack_all(const float* __restrict__ c2w,
        const float* __restrict__ c3w, const float* __restrict__ ow,
        const float* __restrict__ dw, u16* __restrict__ wpk2,
        u16* __restrict__ wpk3, u16* __restrict__ wpko, u16* __restrict__ dwa,
        float* __restrict__ ws0, const float* __restrict__ X,
        const float* __restrict__ Wt, const float* __restrict__ c1b,
        u16* __restrict__ Ybf, float* __restrict__ P1s, float* __restrict__ P1q)
{
    int bx = blockIdx.x;
    int tid = threadIdx.x;

    if (bx >= 4544) {                            // ---- conv1 blocks ----
        const int OT = 16;
        __shared__ float red[4][32];
        int c = bx - 4544;                       // [0,208)
        int xblk = c % 104;
        int o0 = (c / 104) * OT;
        int sblk = (xblk & 7) * 13 + (xblk >> 3);
        if (sblk >= 98) return;
        int t = tid;
        int s = sblk * 256 + t;
        int b = s / SP;
        int sp = s - b * SP;
        int d = sp / 224;
        int r = sp - d * 224;
        int h = r >> 3;
        int w = r & 7;

        float mdh[9]; int odh[9];
        #pragma unroll
        for (int i = 0; i < 3; i++) {
            int dd = d + i - 1;
            float md = ((unsigned)dd < 28u) ? 1.f : 0.f;
            int ddc = min(max(dd, 0), 27);
            #pragma unroll
            for (int j = 0; j < 3; j++) {
                int hh = h + j - 1;
                float mh = ((unsigned)hh < 28u) ? 1.f : 0.f;
                int hhc = min(max(hh, 0), 27);
                mdh[i * 3 + j] = md * mh;
                odh[i * 3 + j] = ddc * 224 + hhc * 8 + w;
            }
        }
        float mw0 = (w > 0) ? 1.f : 0.f;
        float mw2 = (w < 7) ? 1.f : 0.f;

        float acc[OT];
        #pragma unroll
        for (int oo = 0; oo < OT; oo++) acc[oo] = c1b[o0 + oo];

        const float* xc = X + (size_t)b * SP;
        #pragma unroll
        for (int t9 = 0; t9 < 9; t9++) {
            float x0 = xc[odh[t9]];
            float m = mdh[t9];
            float xm = __shfl_up(x0, 1, 64) * (m * mw0);
            float xz = x0 * m;
            float xp = __shfl_down(x0, 1, 64) * (m * mw2);
            #pragma unroll
            for (int oo = 0; oo < OT; oo++) {
                const float* wp = Wt + (size_t)(o0 + oo) * 27 + t9 * 3;
                acc[oo] = fmaf(xm, wp[0], acc[oo]);
                acc[oo] = fmaf(xz, wp[1], acc[oo]);
                acc[oo] = fmaf(xp, wp[2], acc[oo]);
            }
        }
        float sv[OT];
        #pragma unroll
        for (int oo = 0; oo < OT; oo++) sv[oo] = fmaxf(acc[oo], 0.f);

        unsigned pk[8];
        #pragma unroll
        for (int j = 0; j < 8; j++) pk[j] = pk2(sv[2 * j], sv[2 * j + 1]);
        u16* row = Ybf + (size_t)(b * SP + sp) * 32 + o0;
        *(uint4*)(row)     = make_uint4(pk[0], pk[1], pk[2], pk[3]);
        *(uint4*)(row + 8) = make_uint4(pk[4], pk[5], pk[6], pk[7]);

        int l = t & 63, wvv = t >> 6;
        #pragma unroll
        for (int oo = 0; oo < OT; oo++) {
            float ss = sv[oo], qv = ss * ss;
            #pragma unroll
            for (int m = 1; m < 64; m <<= 1) {
                ss += __shfl_xor(ss, m, 64);
                qv += __shfl_xor(qv, m, 64);
            }
            if (l == 0) { red[wvv][oo] = ss; red[wvv][16 + oo] = qv; }
        }
        __syncthreads();
        if (t < 32) {
            float tot = red[0][t] + red[1][t] + red[2][t] + red[3][t];
            if (t < 16) P1s[sblk * 32 + o0 + t] = tot;
            else        P1q[sblk * 32 + o0 + (t - 16)] = tot;
        }
        return;
    }

    if (bx >= 4536) {                            // 8 blocks: zero ws[0..2048)
        int i = (bx - 4536) * 256 + tid;
        if (i < 2048) ws0[i] = 0.f;
        return;
    }
    int idx = bx * 256 + tid;
    if (idx < 55296) {
        // wpk2[t][ot:4][q][r][j]  (CIN=32, NC=1)
        int i = idx;
        int j = i & 7, r = (i >> 3) & 15, q = (i >> 7) & 3;
        int ot = (i >> 9) & 3, t = i >> 11;
        int o = ot * 16 + r, c = q * 8 + j;
        wpk2[i] = f2b(c2w[((size_t)o * 32 + c) * 27 + t]);
    } else if (idx < 276480) {
        // wpk3[t][ot:8][ch:2][q][r][j]  (CIN=64)
        int i = idx - 55296;
        int j = i & 7, r = (i >> 3) & 15, q = (i >> 7) & 3;
        int ch = (i >> 9) & 1, ot = (i >> 10) & 7, t = i >> 13;
        int o = ot * 16 + r, c = ch * 32 + q * 8 + j;
        wpk3[i] = f2b(c3w[((size_t)o * 64 + c) * 27 + t]);
    } else if (idx < 718848) {
        // wpko[t][ot:8][ch:4][q][r][j]  (CIN=128, o>=81 zero)
        int i = idx - 276480;
        int j = i & 7, r = (i >> 3) & 15, q = (i >> 7) & 3;
        int ch = (i >> 9) & 3, ot = (i >> 11) & 7, t = i >> 14;
        int o = ot * 16 + r, c = ch * 32 + q * 8 + j;
        wpko[i] = f2b((o < 81) ? ow[((size_t)o * 128 + c) * 27 + t] : 0.f);
    } else {
        int i = idx - 718848;   // dwa[n][ot][kc][q][r][j]
        int j = i & 7, r = (i >> 3) & 15, q = (i >> 7) & 3;
        int kc = (i >> 9) & 3, ot = (i >> 11) & 7, n = i >> 14;
        int o = ot * 16 + r, c = kc * 32 + q * 8 + j;
        dwa[i] = f2b(dw[((size_t)o * 128 + c) * 27 + n]);
    }
}

// ---------------- MFMA implicit-GEMM conv 3x3x3 (CIN>=32, bf16) ----------------
// BNIN:   apply per-channel affine (from stats) during LDS staging.
// PARTIN: stats come as 98 per-block partials (conv1) -> strided reduce.
// WIDE:   128 outputs in ONE block; wave owns o-tiles wv, wv+4 x 2 d-slices.
// OFFOUT: merged offsets conv; wave = (d-slice, o-tile trio), o in [0,96).
// BNTAIL: blocks fid>=784 run the bn_bf body (write Ybf as uint4) -- rides in
//         the offsets-conv launch since OFFOUT+BNIN reads y3bf directly.
template<int CIN, int OPAD, bool OFFOUT, bool BNIN, bool WIDE, bool PARTIN, bool BNTAIL>
__global__ __launch_bounds__(256) __attribute__((amdgpu_waves_per_eu(1, 4)))
void conv_mfma(const u16* __restrict__ X, const u16* __restrict__ Wpk,
               const float* __restrict__ bias, u16* __restrict__ Ybf,
               float* __restrict__ offs, float* __restrict__ s_sum,
               float* __restrict__ s_sq, const float* __restrict__ in_sum,
               const float* __restrict__ in_sq, const float* __restrict__ in_g,
               const float* __restrict__ in_b)
{
    const int HS = CIN + 8;                 // LDS stride per position (bf16 units)
    const int NOT = OPAD / 16;              // o-tiles in fragment layout
    const int NC = CIN / 32;                // c-chunks in fragment layout
    __shared__ u16 xs[160 * HS];            // [dz 0..3][hz 0..3][wz 0..9][c]
    __shared__ float scin[BNIN ? CIN : 1], shin[BNIN ? CIN : 1];

    int tid = threadIdx.x;
    int fid = blockIdx.x;                   // [0,784) = 8 XCDs x 98
    int g = (fid & 7) * 98 + (fid >> 3);
    int b = g / 196;
    int rem = g - b * 196;
    int d0 = (rem / 14) * 2, h0 = (rem % 14) * 2;

    if (BNIN) {
        if (PARTIN) {
            __shared__ float ps[8][32], pq[8][32];
            int ch = tid & 31, ck = tid >> 5;
            float s = 0.f, qq = 0.f;
            for (int k = ck; k < 98; k += 8) {
                s  += in_sum[k * 32 + ch];
                qq += in_sq[k * 32 + ch];
            }
            ps[ck][ch] = s; pq[ck][ch] = qq;
            __syncthreads();
            if (tid < CIN) {
                float m = 0.f, vq = 0.f;
                #pragma unroll
                for (int k2 = 0; k2 < 8; k2++) { m += ps[k2][tid]; vq += pq[k2][tid]; }
                m *= (1.f / NSP);
                vq = vq * (1.f / NSP) - m * m;
                float sc = in_g[tid] * rsqrtf(vq + EPS);
                scin[tid] = sc;
                shin[tid] = in_b[tid] - m * sc;
            }
            __syncthreads();
        } else {
            if (tid < CIN) {
                float m = in_sum[tid] * (1.f / NSP);
                float v = in_sq[tid] * (1.f / NSP) - m * m;
                float sc = in_g[tid] * rsqrtf(v + EPS);
                scin[tid] = sc;
                shin[tid] = in_b[tid] - m * sc;
            }
            __syncthreads();
        }
    }

    if (BNTAIL && fid >= 784) {
        // ---- bn_bf body: BN-apply y3bf -> x3bf, uint4/lane ----
        int idx = (fid - 784) * 256 + tid;
        uint4 v = ((const uint4*)X)[idx];
        int cb = (idx & (CIN / 8 - 1)) * 8;
        float f0 = b2f_lo(v.x) * scin[cb]     + shin[cb];
        float f1 = b2f_hi(v.x) * scin[cb + 1] + shin[cb + 1];
        float f2 = b2f_lo(v.y) * scin[cb + 2] + shin[cb + 2];
        float f3 = b2f_hi(v.y) * scin[cb + 3] + shin[cb + 3];
        float f4 = b2f_lo(v.z) * scin[cb + 4] + shin[cb + 4];
        float f5 = b2f_hi(v.z) * scin[cb + 5] + shin[cb + 5];
        float f6 = b2f_lo(v.w) * scin[cb + 6] + shin[cb + 6];
        float f7 = b2f_hi(v.w) * scin[cb + 7] + shin[cb + 7];
        uint4 pk;
        pk.x = pk2(f0, f1); pk.y = pk2(f2, f3);
        pk.z = pk2(f4, f5); pk.w = pk2(f6, f7);
        ((uint4*)Ybf)[idx] = pk;
        return;
    }

    const int NCH = CIN / 8;
    for (int idx = tid; idx < 160 * NCH; idx += 256) {
        int pos = idx / NCH, ch = idx - pos * NCH;
        int dz = pos / 40, r2 = pos - dz * 40;
        int hz = r2 / 10, wz = r2 - hz * 10;
        int dd = d0 + dz - 1, hh = h0 + hz - 1, ww = wz - 1;
        uint4 val = make_uint4(0, 0, 0, 0);
        if ((unsigned)dd < 28u && (unsigned)hh < 28u && (unsigned)ww < 8u) {
            val = *(const uint4*)(X + ((size_t)(b * SP + dd * 224 + hh * 8 + ww) * CIN + ch * 8));
            if (BNIN) {
                int cb = ch * 8;
                float f0 = b2f_lo(val.x) * scin[cb]     + shin[cb];
                float f1 = b2f_hi(val.x) * scin[cb + 1] + shin[cb + 1];
                float f2 = b2f_lo(val.y) * scin[cb + 2] + shin[cb + 2];
                float f3 = b2f_hi(val.y) * scin[cb + 3] + shin[cb + 3];
                float f4 = b2f_lo(val.z) * scin[cb + 4] + shin[cb + 4];
                float f5 = b2f_hi(val.z) * scin[cb + 5] + shin[cb + 5];
                float f6 = b2f_lo(val.w) * scin[cb + 6] + shin[cb + 6];
                float f7 = b2f_hi(val.w) * scin[cb + 7] + shin[cb + 7];
                val.x = pk2(f0, f1); val.y = pk2(f2, f3);
                val.z = pk2(f4, f5); val.w = pk2(f6, f7);
            }
        }
        *(uint4*)(xs + pos * HS + ch * 8) = val;
    }
    __syncthreads();

    int l = tid & 63, wv = tid >> 6;
    int q = l >> 4, r = l & 15;
    int hl = r >> 3, wl = r & 7;

    if (OFFOUT) {
        // merged offsets conv: wave = (d-slice dl, o-tile trio ot0..ot0+2)
        int dl = wv >> 1;
        int ot0 = (wv & 1) * 3;
        const u16* ap = xs + ((4 + hl + 1) * 10 + wl + 1) * HS + 8 * q + dl * 40 * HS;
        v4f acc[3];
        acc[0] = (v4f){0.f,0.f,0.f,0.f};
        acc[1] = (v4f){0.f,0.f,0.f,0.f};
        acc[2] = (v4f){0.f,0.f,0.f,0.f};
        #pragma unroll
        for (int t = 0; t < 27; t++) {
            const int koff = ((t / 9) - 1) * 40 + (((t / 3) % 3) - 1) * 10 + (t % 3) - 1;
            const u16* wt = Wpk + ((size_t)(t * NOT + ot0) * NC << 9) + l * 8;
            #pragma unroll
            for (int ch = 0; ch < NC; ch++) {
                v8s a0 = *(const v8s*)(ap + koff * HS + ch * 32);
                v8s b0 = *(const v8s*)(wt + ch * 512);
                v8s b1 = *(const v8s*)(wt + (NC + ch) * 512);
                v8s b2 = *(const v8s*)(wt + (2 * NC + ch) * 512);
                acc[0] = __builtin_amdgcn_mfma_f32_16x16x32_bf16(a0, b0, acc[0], 0, 0, 0);
                acc[1] = __builtin_amdgcn_mfma_f32_16x16x32_bf16(a0, b1, acc[1], 0, 0, 0);
                acc[2] = __builtin_amdgcn_mfma_f32_16x16x32_bf16(a0, b2, acc[2], 0, 0, 0);
            }
        }
        int o0 = ot0 * 16 + r;
        #pragma unroll
        for (int j = 0; j < 3; j++) {
            int o = o0 + 16 * j;
            if (o < 81) {
                float bo = bias[o];
                #pragma unroll
                for (int rg = 0; rg < 4; rg++) {
                    int rowl = q * 4 + rg;
                    int sp = (d0 + dl) * 224 + (h0 + (rowl >> 3)) * 8 + (rowl & 7);
                    offs[((size_t)(b * 81 + o)) * SP + sp] = acc[j][rg] + bo;
                }
            }
        }
        return;
    }

    const u16* a0p = xs + ((4 + hl + 1) * 10 + wl + 1) * HS + 8 * q;  // dl=0
    const u16* a1p = a0p + 40 * HS;                                   // dl=1

    if (WIDE) {
        // 128 outputs per block: wave owns o-tiles wv and wv+4 (o, o+64)
        v4f acc[2][2];                       // [oti][dl]
        acc[0][0] = (v4f){0.f,0.f,0.f,0.f}; acc[0][1] = (v4f){0.f,0.f,0.f,0.f};
        acc[1][0] = (v4f){0.f,0.f,0.f,0.f}; acc[1][1] = (v4f){0.f,0.f,0.f,0.f};
        #pragma unroll
        for (int t = 0; t < 27; t++) {
            const int koff = ((t / 9) - 1) * 40 + (((t / 3) % 3) - 1) * 10 + (t % 3) - 1;
            const u16* wt  = Wpk + ((size_t)(t * NOT + wv) * NC << 9) + l * 8;
            const u16* wt2 = wt + (size_t)4 * NC * 512;      // ot = wv+4
            #pragma unroll
            for (int ch = 0; ch < NC; ch++) {
                v8s a0 = *(const v8s*)(a0p + koff * HS + ch * 32);
                v8s a1 = *(const v8s*)(a1p + koff * HS + ch * 32);
                v8s b0 = *(const v8s*)(wt + ch * 512);
                v8s b1 = *(const v8s*)(wt2 + ch * 512);
                acc[0][0] = __builtin_amdgcn_mfma_f32_16x16x32_bf16(a0, b0, acc[0][0], 0, 0, 0);
                acc[0][1] = __builtin_amdgcn_mfma_f32_16x16x32_bf16(a1, b0, acc[0][1], 0, 0, 0);
                acc[1][0] = __builtin_amdgcn_mfma_f32_16x16x32_bf16(a0, b1, acc[1][0], 0, 0, 0);
                acc[1][1] = __builtin_amdgcn_mfma_f32_16x16x32_bf16(a1, b1, acc[1][1], 0, 0, 0);
            }
        }
        #pragma unroll
        for (int oti = 0; oti < 2; oti++) {
            int o_base = wv * 16 + oti * 64;
            int oo = o_base + r;
            float bo = bias[oo];
            float rs = 0.f, rq = 0.f;
            #pragma unroll
            for (int s2 = 0; s2 < 2; s2++) {
                v4f A = acc[oti][s2];
                #pragma unroll
                for (int rg = 0; rg < 4; rg++) {
                    int rowl = q * 4 + rg;
                    int sp = (d0 + s2) * 224 + (h0 + (rowl >> 3)) * 8 + (rowl & 7);
                    float v = fmaxf(A[rg] + bo, 0.f);
                    Ybf[(size_t)(b * SP + sp) * OPAD + oo] = f2b(v);
                    rs += v; rq += v * v;
                }
            }
            rs += __shfl_xor(rs, 16, 64); rs += __shfl_xor(rs, 32, 64);
            rq += __shfl_xor(rq, 16, 64); rq += __shfl_xor(rq, 32, 64);
            if (l < 16) { atomicAdd(&s_sum[o_base + l], rs); atomicAdd(&s_sq[o_base + l], rq); }
        }
        return;
    }

    int o_base = blockIdx.y * 64 + wv * 16;
    int o = o_base + r;
    int otg = o_base >> 4;                   // fragment o-tile index

    v4f acc0 = {0.f, 0.f, 0.f, 0.f}, acc1 = {0.f, 0.f, 0.f, 0.f};
    #pragma unroll
    for (int t = 0; t < 27; t++) {
        const int koff = ((t / 9) - 1) * 40 + (((t / 3) % 3) - 1) * 10 + (t % 3) - 1;
        const u16* wt = Wpk + ((size_t)(t * NOT + otg) * NC << 9) + l * 8;
        #pragma unroll
        for (int ch = 0; ch < NC; ch++) {
            v8s a0 = *(const v8s*)(a0p + koff * HS + ch * 32);
            v8s a1 = *(const v8s*)(a1p + koff * HS + ch * 32);
            v8s bf = *(const v8s*)(wt + ch * 512);
            acc0 = __builtin_amdgcn_mfma_f32_16x16x32_bf16(a0, bf, acc0, 0, 0, 0);
            acc1 = __builtin_amdgcn_mfma_f32_16x16x32_bf16(a1, bf, acc1, 0, 0, 0);
        }
    }

    {
        float bo = bias[o];
        float rs = 0.f, rq = 0.f;
        #pragma unroll
        for (int s2 = 0; s2 < 2; s2++) {
            v4f A = s2 ? acc1 : acc0;
            #pragma unroll
            for (int rg = 0; rg < 4; rg++) {
                int rowl = q * 4 + rg;
                int sp = (d0 + s2) * 224 + (h0 + (rowl >> 3)) * 8 + (rowl & 7);
                float v = fmaxf(A[rg] + bo, 0.f);
                Ybf[(size_t)(b * SP + sp) * OPAD + o] = f2b(v);
                rs += v; rq += v * v;
            }
        }
        rs += __shfl_xor(rs, 16, 64); rs += __shfl_xor(rs, 32, 64);
        rq += __shfl_xor(rq, 16, 64); rq += __shfl_xor(rq, 32, 64);
        if (l < 16) { atomicAdd(&s_sum[o_base + l], rs); atomicAdd(&s_sq[o_base + l], rq); }
    }
}

// ---------------- deformable conv (MFMA) -- R25: position-split tiles ----------------
// R21 per-tap structure verbatim (2-tap barrier sets, scalar-fmaf sample); tiles are
// now 16 positions (2 h-rows) instead of 32 -> 1568 dense blocks (launch 1600).
// Each block is fully independent (own taps, own channels, own pooled sums into the
// existing atomics) -- NO cross-block partials (R24's global-atomic partials caused
// a 206MB write storm). LDS 33 -> ~17KB, grid 2x: raises resident blocks/CU ~2x.
__global__ __launch_bounds__(256) __attribute__((amdgpu_waves_per_eu(1, 4)))
void deform_pool(const u16* __restrict__ Ht, const float* __restrict__ OFF,
                 const u16* __restrict__ Wa, const float* __restrict__ db,
                 float* __restrict__ pooledraw, float* __restrict__ sumsq4)
{
    __shared__ float offs_lds[81 * 16];     // [ch][p]
    __shared__ int ig_s[2][16][8][2];       // [tap][p][corner][{idx, g bits}]
    __shared__ u16 Vb[2][16][136];          // [tap][p][c] bf16, row pad +8
    __shared__ float reds[128], redq[128];

    int bid = blockIdx.x;          // [0,1600)
    int xcd = bid & 7;
    int local = bid >> 3;          // [0,200)
    if (local >= 196) return;
    int b = xcd >> 1;
    int d = (xcd & 1) * 14 + local / 14;
    int h0 = (local % 14) * 2;

    int t = threadIdx.x;
    if (t < 128) { reds[t] = 0.f; redq[t] = 0.f; }

    int gp = (t >> 3) & 15, gcr = t & 7;           // geometry role (t<128)
    int glh = gp >> 3, gw = gp & 7, gh = h0 + glh;
    int co = t & 15, pg = t >> 4;                  // sample role: c-oct, position
    int l = t & 63, wv = t >> 6;                   // MFMA role
    int q = l >> 4, r = l & 15;

    v4f acc[2];                                    // [o-tile] (single p-tile)
    acc[0] = (v4f){0.f,0.f,0.f,0.f};
    acc[1] = (v4f){0.f,0.f,0.f,0.f};

    const u16* hb = Ht + (size_t)b * SP * 128;

    // ---- stage offsets for this block's 16 positions (coalesced, once) ----
    for (int i = t; i < 1296; i += 256) {
        int ch = i >> 4, p = i & 15;
        offs_lds[i] = OFF[(size_t)b * 81 * SP + (size_t)ch * SP
                          + d * 224 + (h0 + (p >> 3)) * 8 + (p & 7)];
    }

    auto GEOM = [&](int n, int tap) {
        int kd = n / 9 - 1, kh = (n / 3) % 3 - 1, kw = n % 3 - 1;
        float od  = offs_lds[n * 16 + gp];
        float oh  = offs_lds[(27 + n) * 16 + gp];
        float owv = offs_lds[(54 + n) * 16 + gp];
        float pd = fminf(fmaxf((float)(d + 1 + kd) + od, 0.f), 29.f);
        float ph = fminf(fmaxf((float)(gh + 1 + kh) + oh, 0.f), 29.f);
        float pw = fminf(fmaxf((float)(gw + 1 + kw) + owv, 0.f), 9.f);
        float qd = fminf(floorf(pd), 28.f);
        float qh = fminf(floorf(ph), 28.f);
        float qw = fminf(floorf(pw), 8.f);
        float td = fminf(pd - qd, 1.f);
        float th = fminf(ph - qh, 1.f);
        float tw = fminf(pw - qw, 1.f);
        int iqd = (int)qd - 1, iqh = (int)qh - 1, iqw = (int)qw - 1;
        int i = gcr >> 2, j = (gcr >> 1) & 1, k = gcr & 1;
        int du = iqd + i, hu = iqh + j, wu = iqw + k;
        bool val = (unsigned)du < 28u && (unsigned)hu < 28u && (unsigned)wu < 8u;
        float gg = (i ? td : 1.f - td) * (j ? th : 1.f - th) * (k ? tw : 1.f - tw);
        ig_s[tap][gp][gcr][0] = val ? (du * 224 + hu * 8 + wu) : 0;
        ig_s[tap][gp][gcr][1] = __float_as_int(val ? gg : 0.f);
    };

    auto SAMPLE = [&](int tap) {
        float va[8] = {0.f,0.f,0.f,0.f,0.f,0.f,0.f,0.f};
        #pragma unroll
        for (int cr = 0; cr < 8; cr++) {
            int2 pr = *(const int2*)&ig_s[tap][pg][cr][0];
            float gg = __int_as_float(pr.y);
            uint4 xv = *(const uint4*)(hb + (size_t)pr.x * 128 + co * 8);
            va[0] = fmaf(gg, b2f_lo(xv.x), va[0]);
            va[1] = fmaf(gg, b2f_hi(xv.x), va[1]);
            va[2] = fmaf(gg, b2f_lo(xv.y), va[2]);
            va[3] = fmaf(gg, b2f_hi(xv.y), va[3]);
            va[4] = fmaf(gg, b2f_lo(xv.z), va[4]);
            va[5] = fmaf(gg, b2f_hi(xv.z), va[5]);
            va[6] = fmaf(gg, b2f_lo(xv.w), va[6]);
            va[7] = fmaf(gg, b2f_hi(xv.w), va[7]);
        }
        uint4 pk;
        pk.x = pk2(va[0], va[1]); pk.y = pk2(va[2], va[3]);
        pk.z = pk2(va[4], va[5]); pk.w = pk2(va[6], va[7]);
        *(uint4*)&Vb[tap][pg][co * 8] = pk;
    };

    auto MFMA_TAP = [&](int n, int tap) {
        const u16* wn = Wa + (size_t)n * 16384;
        #pragma unroll
        for (int oti = 0; oti < 2; oti++) {
            int ot = wv * 2 + oti;
            #pragma unroll
            for (int kc = 0; kc < 4; kc++) {
                v8s af = *(const v8s*)(wn + ((((ot * 4 + kc) * 4 + q) * 16 + r) * 8));
                v8s bf0 = *(const v8s*)&Vb[tap][r][kc * 32 + q * 8];
                acc[oti] = __builtin_amdgcn_mfma_f32_16x16x32_bf16(af, bf0, acc[oti], 0, 0, 0);
            }
        }
    };

    for (int it = 0; it < 14; it++) {
        int n0 = it * 2, n1 = n0 + 1;
        bool two = (n1 < 27);                      // uniform across block
        __syncthreads();   // prev MFMA done reading Vb (and offs_lds ready, it=0)
        if (t < 128) {
            GEOM(n0, 0);
            if (two) GEOM(n1, 1);
        }
        __syncthreads();
        SAMPLE(0);
        if (two) SAMPLE(1);
        __syncthreads();
        MFMA_TAP(n0, 0);
        if (two) MFMA_TAP(n1, 1);
    }

    // ---- epilogue: bias + relu + pooled sum / sumsq over 16 positions ----
    #pragma unroll
    for (int oti = 0; oti < 2; oti++) {
        #pragma unroll
        for (int rg = 0; rg < 4; rg++) {
            int o = (wv * 2 + oti) * 16 + q * 4 + rg;
            float bo = db[o];
            float v0 = fmaxf(acc[oti][rg] + bo, 0.f);
            float s = v0, qq = v0 * v0;
            s += __shfl_xor(s, 1, 64);  qq += __shfl_xor(qq, 1, 64);
            s += __shfl_xor(s, 2, 64);  qq += __shfl_xor(qq, 2, 64);
            s += __shfl_xor(s, 4, 64);  qq += __shfl_xor(qq, 4, 64);
            s += __shfl_xor(s, 8, 64);  qq += __shfl_xor(qq, 8, 64);
            if (r == 0) { atomicAdd(&reds[o], s); atomicAdd(&redq[o], qq); }
        }
    }
    __syncthreads();
    if (t < 128) {
        atomicAdd(&pooledraw[b * 128 + t], reds[t]);
        atomicAdd(&sumsq4[t], redq[t]);
    }
}

// ---------------- tail kernel: BN4+pool+FC+log_softmax (offsets already in d_out) ----
__global__ __launch_bounds__(256) void final_head_emit(const float* __restrict__ pooledraw,
        const float* __restrict__ sumsq4, const float* __restrict__ g4,
        const float* __restrict__ b4, const float* __restrict__ fcw,
        const float* __restrict__ fcb, float* __restrict__ out)
{
    int t = threadIdx.x;
    __shared__ float pooled_s[4][128];
    __shared__ float logits[4][10];
    if (t < 128) {
        float s0 = pooledraw[t], s1 = pooledraw[128 + t];
        float s2 = pooledraw[256 + t], s3 = pooledraw[384 + t];
        float tot = s0 + s1 + s2 + s3;
        float m  = tot * (1.f / NSP);
        float v  = sumsq4[t] * (1.f / NSP) - m * m;
        float sc = g4[t] * rsqrtf(v + EPS);
        float sh = b4[t] - m * sc;
        pooled_s[0][t] = s0 * (1.f / SP) * sc + sh;
        pooled_s[1][t] = s1 * (1.f / SP) * sc + sh;
        pooled_s[2][t] = s2 * (1.f / SP) * sc + sh;
        pooled_s[3][t] = s3 * (1.f / SP) * sc + sh;
    }
    __syncthreads();
    if (t < 40) {
        int b = t / 10, j = t % 10;
        float l = fcb[j];
        for (int c = 0; c < 128; c++) l = fmaf(pooled_s[b][c], fcw[j * 128 + c], l);
        logits[b][j] = l;
    }
    __syncthreads();
    if (t < 4) {
        float mx = -1e30f;
        for (int j = 0; j < 10; j++) mx = fmaxf(mx, logits[t][j]);
        float se = 0.f;
        for (int j = 0; j < 10; j++) se += expf(logits[t][j] - mx);
        float lse = mx + logf(se);
        for (int j = 0; j < 10; j++) out[t * 10 + j] = logits[t][j] - lse;
    }
}

extern "C" void kernel_launch(void* const* d_in, const int* in_sizes, int n_in,
                              void* d_out, int out_size, void* d_ws, size_t ws_size,
                              hipStream_t stream)
{
    (void)in_sizes; (void)n_in; (void)out_size; (void)ws_size;
    const float* x   = (const float*)d_in[0];
    const float* c1w = (const float*)d_in[1];
    const float* c1b = (const float*)d_in[2];
    const float* g1  = (const float*)d_in[3];
    const float* b1  = (const float*)d_in[4];
    const float* c2w = (const float*)d_in[5];
    const float* c2b = (const float*)d_in[6];
    const float* g2  = (const float*)d_in[7];
    const float* b2  = (const float*)d_in[8];
    const float* c3w = (const float*)d_in[9];
    const float* c3b = (const float*)d_in[10];
    const float* g3  = (const float*)d_in[11];
    const float* b3  = (const float*)d_in[12];
    const float* ow  = (const float*)d_in[13];
    const float* ob  = (const float*)d_in[14];
    const float* dw  = (const float*)d_in[15];
    const float* db  = (const float*)d_in[16];
    const float* g4  = (const float*)d_in[17];
    const float* b4  = (const float*)d_in[18];
    const float* fcw = (const float*)d_in[19];
    const float* fcb = (const float*)d_in[20];

    float* ws = (float*)d_ws;
    float* S2 = ws + 64,  *Q2 = ws + 128;
    float* S3 = ws + 192, *Q3 = ws + 320;
    float* PO = ws + 448;            // 4*128
    float* Q4 = ws + 960;            // 128
    float* P1s = ws + 4096;          // 98*32 conv1 partial sums (no zero-init needed)
    float* P1q = ws + 7232;          // 98*32 conv1 partial sumsq
    u16* y1bf = (u16*)(ws + 16384);        // NSP*32
    u16* y2bf = y1bf + 802816;             // NSP*64
    u16* y3bf = y2bf + 1605632;            // NSP*128
    u16* x3bf = y3bf + 3211264;
    u16* wpk2 = x3bf + 3211264;            // 27*64*32
    u16* wpk3 = wpk2 + 55296;              // 27*128*64
    u16* wpko = wpk3 + 221184;             // 27*128*128 (o>=81 zero)
    u16* dwa  = wpko + 442368;             // 27*128*128 A-frag layout bf16

    float* outf = (float*)d_out;
    float* offp = outf + 40;               // offsets written DIRECTLY to d_out

    // L1: prepack + ws-zero + conv1 (independent; overlapped in one launch)
    prepack_all<<<4752, 256, 0, stream>>>(c2w, c3w, ow, dw, wpk2, wpk3, wpko, dwa,
                                          ws, x, c1w, c1b, y1bf, P1s, P1q);

    // L2: conv2 (BN1 from conv1 partials)
    conv_mfma<32, 64, false, true, false, true, false><<<784, 256, 0, stream>>>(
        y1bf, wpk2, c2b, y2bf, nullptr, S2, Q2, P1s, P1q, g1, b1);

    // L3: conv3 WIDE (BN2 from atomics)
    conv_mfma<64, 128, false, true, true, false, false><<<784, 256, 0, stream>>>(
        y2bf, wpk3, c3b, y3bf, nullptr, S3, Q3, S2, Q2, g2, b2);

    // L4: offsets conv (BN3 applied in staging, reads y3bf) + bn_bf tail blocks
    //     (write x3bf for deform) -- independent, merged in one launch
    conv_mfma<128, 128, true, true, false, false, true><<<2352, 256, 0, stream>>>(
        y3bf, wpko, ob, x3bf, offp, nullptr, nullptr, S3, Q3, g3, b3);

    // L5: deform, position-split tiles (grid 1600, fully independent blocks)
    deform_pool<<<1600, 256, 0, stream>>>(x3bf, offp, dwa, db, PO, Q4);

    // L6: head
    final_head_emit<<<1, 256, 0, stream>>>(PO, Q4, g4, b4, fcw, fcb, outf);
}

// Round 11
// 364.036 us; speedup vs baseline: 1.8438x; 1.0019x over previous
//
#include <hip/hip_runtime.h>
#include <hip/hip_bf16.h>
#include <math.h>

#define BB 4
#define SP 6272      // 28*28*8 spatial per batch
#define NSP 25088    // BB*SP
#define EPS 1e-5f

typedef unsigned short u16;
typedef __attribute__((ext_vector_type(8))) short v8s;   // 8 bf16 (4 VGPRs)
typedef __attribute__((ext_vector_type(4))) float v4f;   // MFMA accumulator

__device__ __forceinline__ u16 f2b(float f) {            // fp32 -> bf16 RNE
    unsigned u = __float_as_uint(f);
    return (u16)((u + 0x7fffu + ((u >> 16) & 1u)) >> 16);
}
__device__ __forceinline__ float b2f(u16 s) {
    return __uint_as_float(((unsigned)s) << 16);
}
__device__ __forceinline__ float b2f_lo(unsigned x) { return __uint_as_float(x << 16); }
__device__ __forceinline__ float b2f_hi(unsigned x) { return __uint_as_float(x & 0xffff0000u); }
__device__ __forceinline__ unsigned pk2(float a, float b) {   // v_cvt_pk_bf16_f32
    __hip_bfloat162 h = __float22bfloat162_rn(make_float2(a, b));
    unsigned u;
    __builtin_memcpy(&u, &h, 4);
    return u;
}

// ---------------- merged launch 1: weight prepack + ws zeroing + conv1 ----------------
// conv1 (1->32, shuffle form) rides as blocks [4544, 4752); data-independent of the
// prepack work, so it overlaps. conv1 writes PER-BLOCK partial stats (P1s/P1q,
// no atomics -> no same-launch zero-init dependency); conv2's preamble reduces them.
// Weights are packed in FRAGMENT layout [t][ot][ch][q][r][j] (lane l reads 16B at
// base + l*8): one coalesced 1KB request per B-load (R20 fix: -120us).
__global__ __launch_bounds__(256) void prepack_all(const float* __restrict__ c2w,
        const float* __restrict__ c3w, const float* __restrict__ ow,
        const float* __restrict__ dw, u16* __restrict__ wpk2,
        u16* __restrict__ wpk3, u16* __restrict__ wpko, u16* __restrict__ dwa,
        float* __restrict__ ws0, const float* __restrict__ X,
        const float* __restrict__ Wt, const float* __restrict__ c1b,
        u16* __restrict__ Ybf, float* __restrict__ P1s, float* __restrict__ P1q)
{
    int bx = blockIdx.x;
    int tid = threadIdx.x;

    if (bx >= 4544) {                            // ---- conv1 blocks ----
        const int OT = 16;
        __shared__ float red[4][32];
        int c = bx - 4544;                       // [0,208)
        int xblk = c % 104;
        int o0 = (c / 104) * OT;
        int sblk = (xblk & 7) * 13 + (xblk >> 3);
        if (sblk >= 98) return;
        int t = tid;
        int s = sblk * 256 + t;
        int b = s / SP;
        int sp = s - b * SP;
        int d = sp / 224;
        int r = sp - d * 224;
        int h = r >> 3;
        int w = r & 7;

        float mdh[9]; int odh[9];
        #pragma unroll
        for (int i = 0; i < 3; i++) {
            int dd = d + i - 1;
            float md = ((unsigned)dd < 28u) ? 1.f : 0.f;
            int ddc = min(max(dd, 0), 27);
            #pragma unroll
            for (int j = 0; j < 3; j++) {
                int hh = h + j - 1;
                float mh = ((unsigned)hh < 28u) ? 1.f : 0.f;
                int hhc = min(max(hh, 0), 27);
                mdh[i * 3 + j] = md * mh;
                odh[i * 3 + j] = ddc * 224 + hhc * 8 + w;
            }
        }
        float mw0 = (w > 0) ? 1.f : 0.f;
        float mw2 = (w < 7) ? 1.f : 0.f;

        float acc[OT];
        #pragma unroll
        for (int oo = 0; oo < OT; oo++) acc[oo] = c1b[o0 + oo];

        const float* xc = X + (size_t)b * SP;
        #pragma unroll
        for (int t9 = 0; t9 < 9; t9++) {
            float x0 = xc[odh[t9]];
            float m = mdh[t9];
            float xm = __shfl_up(x0, 1, 64) * (m * mw0);
            float xz = x0 * m;
            float xp = __shfl_down(x0, 1, 64) * (m * mw2);
            #pragma unroll
            for (int oo = 0; oo < OT; oo++) {
                const float* wp = Wt + (size_t)(o0 + oo) * 27 + t9 * 3;
                acc[oo] = fmaf(xm, wp[0], acc[oo]);
                acc[oo] = fmaf(xz, wp[1], acc[oo]);
                acc[oo] = fmaf(xp, wp[2], acc[oo]);
            }
        }
        float sv[OT];
        #pragma unroll
        for (int oo = 0; oo < OT; oo++) sv[oo] = fmaxf(acc[oo], 0.f);

        unsigned pk[8];
        #pragma unroll
        for (int j = 0; j < 8; j++) pk[j] = pk2(sv[2 * j], sv[2 * j + 1]);
        u16* row = Ybf + (size_t)(b * SP + sp) * 32 + o0;
        *(uint4*)(row)     = make_uint4(pk[0], pk[1], pk[2], pk[3]);
        *(uint4*)(row + 8) = make_uint4(pk[4], pk[5], pk[6], pk[7]);

        int l = t & 63, wvv = t >> 6;
        #pragma unroll
        for (int oo = 0; oo < OT; oo++) {
            float ss = sv[oo], qv = ss * ss;
            #pragma unroll
            for (int m = 1; m < 64; m <<= 1) {
                ss += __shfl_xor(ss, m, 64);
                qv += __shfl_xor(qv, m, 64);
            }
            if (l == 0) { red[wvv][oo] = ss; red[wvv][16 + oo] = qv; }
        }
        __syncthreads();
        if (t < 32) {
            float tot = red[0][t] + red[1][t] + red[2][t] + red[3][t];
            if (t < 16) P1s[sblk * 32 + o0 + t] = tot;
            else        P1q[sblk * 32 + o0 + (t - 16)] = tot;
        }
        return;
    }

    if (bx >= 4536) {                            // 8 blocks: zero ws[0..2048)
        int i = (bx - 4536) * 256 + tid;
        if (i < 2048) ws0[i] = 0.f;
        return;
    }
    int idx = bx * 256 + tid;
    if (idx < 55296) {
        // wpk2[t][ot:4][q][r][j]  (CIN=32, NC=1)
        int i = idx;
        int j = i & 7, r = (i >> 3) & 15, q = (i >> 7) & 3;
        int ot = (i >> 9) & 3, t = i >> 11;
        int o = ot * 16 + r, c = q * 8 + j;
        wpk2[i] = f2b(c2w[((size_t)o * 32 + c) * 27 + t]);
    } else if (idx < 276480) {
        // wpk3[t][ot:8][ch:2][q][r][j]  (CIN=64)
        int i = idx - 55296;
        int j = i & 7, r = (i >> 3) & 15, q = (i >> 7) & 3;
        int ch = (i >> 9) & 1, ot = (i >> 10) & 7, t = i >> 13;
        int o = ot * 16 + r, c = ch * 32 + q * 8 + j;
        wpk3[i] = f2b(c3w[((size_t)o * 64 + c) * 27 + t]);
    } else if (idx < 718848) {
        // wpko[t][ot:8][ch:4][q][r][j]  (CIN=128, o>=81 zero)
        int i = idx - 276480;
        int j = i & 7, r = (i >> 3) & 15, q = (i >> 7) & 3;
        int ch = (i >> 9) & 3, ot = (i >> 11) & 7, t = i >> 14;
        int o = ot * 16 + r, c = ch * 32 + q * 8 + j;
        wpko[i] = f2b((o < 81) ? ow[((size_t)o * 128 + c) * 27 + t] : 0.f);
    } else {
        int i = idx - 718848;   // dwa[n][ot][kc][q][r][j]
        int j = i & 7, r = (i >> 3) & 15, q = (i >> 7) & 3;
        int kc = (i >> 9) & 3, ot = (i >> 11) & 7, n = i >> 14;
        int o = ot * 16 + r, c = kc * 32 + q * 8 + j;
        dwa[i] = f2b(dw[((size_t)o * 128 + c) * 27 + n]);
    }
}

// ---------------- MFMA implicit-GEMM conv 3x3x3 (CIN>=32, bf16) ----------------
// BNIN:   apply per-channel affine (from stats) during LDS staging.
// PARTIN: stats come as 98 per-block partials (conv1) -> strided reduce.
// WIDE:   128 outputs in ONE block (kept for reference; unused after R26).
// OFFOUT: merged offsets conv; wave = (d-slice, o-tile trio), o in [0,96).
// BNTAIL: blocks fid>=784 run the bn_bf body (write Ybf as uint4).
// SPLIT2: o-channel split y=2: wave = (d-slice, o-tile = y*2+(wv&1)); raises
//         grid to 1568 for occupancy (R26: convs were grid-limited at 3/CU).
// waves_per_eu(1,8): min 1 (no VGPR restriction), cap 8 -> allows 6 blocks/CU.
template<int CIN, int OPAD, bool OFFOUT, bool BNIN, bool WIDE, bool PARTIN,
         bool BNTAIL, bool SPLIT2>
__global__ __launch_bounds__(256) __attribute__((amdgpu_waves_per_eu(1, 8)))
void conv_mfma(const u16* __restrict__ X, const u16* __restrict__ Wpk,
               const float* __restrict__ bias, u16* __restrict__ Ybf,
               float* __restrict__ offs, float* __restrict__ s_sum,
               float* __restrict__ s_sq, const float* __restrict__ in_sum,
               const float* __restrict__ in_sq, const float* __restrict__ in_g,
               const float* __restrict__ in_b)
{
    const int HS = CIN + 8;                 // LDS stride per position (bf16 units)
    const int NOT = OPAD / 16;              // o-tiles in fragment layout
    const int NC = CIN / 32;                // c-chunks in fragment layout
    __shared__ u16 xs[160 * HS];            // [dz 0..3][hz 0..3][wz 0..9][c]
    __shared__ float scin[BNIN ? CIN : 1], shin[BNIN ? CIN : 1];

    int tid = threadIdx.x;
    int fid = blockIdx.x;                   // [0,784) = 8 XCDs x 98
    int g = (fid & 7) * 98 + (fid >> 3);
    int b = g / 196;
    int rem = g - b * 196;
    int d0 = (rem / 14) * 2, h0 = (rem % 14) * 2;

    if (BNIN) {
        if (PARTIN) {
            __shared__ float ps[8][32], pq[8][32];
            int ch = tid & 31, ck = tid >> 5;
            float s = 0.f, qq = 0.f;
            for (int k = ck; k < 98; k += 8) {
                s  += in_sum[k * 32 + ch];
                qq += in_sq[k * 32 + ch];
            }
            ps[ck][ch] = s; pq[ck][ch] = qq;
            __syncthreads();
            if (tid < CIN) {
                float m = 0.f, vq = 0.f;
                #pragma unroll
                for (int k2 = 0; k2 < 8; k2++) { m += ps[k2][tid]; vq += pq[k2][tid]; }
                m *= (1.f / NSP);
                vq = vq * (1.f / NSP) - m * m;
                float sc = in_g[tid] * rsqrtf(vq + EPS);
                scin[tid] = sc;
                shin[tid] = in_b[tid] - m * sc;
            }
            __syncthreads();
        } else {
            if (tid < CIN) {
                float m = in_sum[tid] * (1.f / NSP);
                float v = in_sq[tid] * (1.f / NSP) - m * m;
                float sc = in_g[tid] * rsqrtf(v + EPS);
                scin[tid] = sc;
                shin[tid] = in_b[tid] - m * sc;
            }
            __syncthreads();
        }
    }

    if (BNTAIL && fid >= 784) {
        // ---- bn_bf body: BN-apply y3bf -> x3bf, uint4/lane ----
        int idx = (fid - 784) * 256 + tid;
        uint4 v = ((const uint4*)X)[idx];
        int cb = (idx & (CIN / 8 - 1)) * 8;
        float f0 = b2f_lo(v.x) * scin[cb]     + shin[cb];
        float f1 = b2f_hi(v.x) * scin[cb + 1] + shin[cb + 1];
        float f2 = b2f_lo(v.y) * scin[cb + 2] + shin[cb + 2];
        float f3 = b2f_hi(v.y) * scin[cb + 3] + shin[cb + 3];
        float f4 = b2f_lo(v.z) * scin[cb + 4] + shin[cb + 4];
        float f5 = b2f_hi(v.z) * scin[cb + 5] + shin[cb + 5];
        float f6 = b2f_lo(v.w) * scin[cb + 6] + shin[cb + 6];
        float f7 = b2f_hi(v.w) * scin[cb + 7] + shin[cb + 7];
        uint4 pk;
        pk.x = pk2(f0, f1); pk.y = pk2(f2, f3);
        pk.z = pk2(f4, f5); pk.w = pk2(f6, f7);
        ((uint4*)Ybf)[idx] = pk;
        return;
    }

    const int NCH = CIN / 8;
    for (int idx = tid; idx < 160 * NCH; idx += 256) {
        int pos = idx / NCH, ch = idx - pos * NCH;
        int dz = pos / 40, r2 = pos - dz * 40;
        int hz = r2 / 10, wz = r2 - hz * 10;
        int dd = d0 + dz - 1, hh = h0 + hz - 1, ww = wz - 1;
        uint4 val = make_uint4(0, 0, 0, 0);
        if ((unsigned)dd < 28u && (unsigned)hh < 28u && (unsigned)ww < 8u) {
            val = *(const uint4*)(X + ((size_t)(b * SP + dd * 224 + hh * 8 + ww) * CIN + ch * 8));
            if (BNIN) {
                int cb = ch * 8;
                float f0 = b2f_lo(val.x) * scin[cb]     + shin[cb];
                float f1 = b2f_hi(val.x) * scin[cb + 1] + shin[cb + 1];
                float f2 = b2f_lo(val.y) * scin[cb + 2] + shin[cb + 2];
                float f3 = b2f_hi(val.y) * scin[cb + 3] + shin[cb + 3];
                float f4 = b2f_lo(val.z) * scin[cb + 4] + shin[cb + 4];
                float f5 = b2f_hi(val.z) * scin[cb + 5] + shin[cb + 5];
                float f6 = b2f_lo(val.w) * scin[cb + 6] + shin[cb + 6];
                float f7 = b2f_hi(val.w) * scin[cb + 7] + shin[cb + 7];
                val.x = pk2(f0, f1); val.y = pk2(f2, f3);
                val.z = pk2(f4, f5); val.w = pk2(f6, f7);
            }
        }
        *(uint4*)(xs + pos * HS + ch * 8) = val;
    }
    __syncthreads();

    int l = tid & 63, wv = tid >> 6;
    int q = l >> 4, r = l & 15;
    int hl = r >> 3, wl = r & 7;

    if (OFFOUT) {
        // merged offsets conv: wave = (d-slice dl, o-tile trio ot0..ot0+2)
        int dl = wv >> 1;
        int ot0 = (wv & 1) * 3;
        const u16* ap = xs + ((4 + hl + 1) * 10 + wl + 1) * HS + 8 * q + dl * 40 * HS;
        v4f acc[3];
        acc[0] = (v4f){0.f,0.f,0.f,0.f};
        acc[1] = (v4f){0.f,0.f,0.f,0.f};
        acc[2] = (v4f){0.f,0.f,0.f,0.f};
        #pragma unroll
        for (int t = 0; t < 27; t++) {
            const int koff = ((t / 9) - 1) * 40 + (((t / 3) % 3) - 1) * 10 + (t % 3) - 1;
            const u16* wt = Wpk + ((size_t)(t * NOT + ot0) * NC << 9) + l * 8;
            #pragma unroll
            for (int ch = 0; ch < NC; ch++) {
                v8s a0 = *(const v8s*)(ap + koff * HS + ch * 32);
                v8s b0 = *(const v8s*)(wt + ch * 512);
                v8s b1 = *(const v8s*)(wt + (NC + ch) * 512);
                v8s b2 = *(const v8s*)(wt + (2 * NC + ch) * 512);
                acc[0] = __builtin_amdgcn_mfma_f32_16x16x32_bf16(a0, b0, acc[0], 0, 0, 0);
                acc[1] = __builtin_amdgcn_mfma_f32_16x16x32_bf16(a0, b1, acc[1], 0, 0, 0);
                acc[2] = __builtin_amdgcn_mfma_f32_16x16x32_bf16(a0, b2, acc[2], 0, 0, 0);
            }
        }
        int o0 = ot0 * 16 + r;
        #pragma unroll
        for (int j = 0; j < 3; j++) {
            int o = o0 + 16 * j;
            if (o < 81) {
                float bo = bias[o];
                #pragma unroll
                for (int rg = 0; rg < 4; rg++) {
                    int rowl = q * 4 + rg;
                    int sp = (d0 + dl) * 224 + (h0 + (rowl >> 3)) * 8 + (rowl & 7);
                    offs[((size_t)(b * 81 + o)) * SP + sp] = acc[j][rg] + bo;
                }
            }
        }
        return;
    }

    if (SPLIT2) {
        // o-channel split: wave = (d-slice dl, o-tile ot = y*2 + (wv&1))
        int dl = wv >> 1;
        int ot = blockIdx.y * 2 + (wv & 1);
        const u16* ap = xs + ((4 + hl + 1) * 10 + wl + 1) * HS + 8 * q + dl * 40 * HS;
        v4f acc = {0.f, 0.f, 0.f, 0.f};
        #pragma unroll
        for (int t = 0; t < 27; t++) {
            const int koff = ((t / 9) - 1) * 40 + (((t / 3) % 3) - 1) * 10 + (t % 3) - 1;
            const u16* wt = Wpk + ((size_t)(t * NOT + ot) * NC << 9) + l * 8;
            #pragma unroll
            for (int ch = 0; ch < NC; ch++) {
                v8s a0 = *(const v8s*)(ap + koff * HS + ch * 32);
                v8s bf = *(const v8s*)(wt + ch * 512);
                acc = __builtin_amdgcn_mfma_f32_16x16x32_bf16(a0, bf, acc, 0, 0, 0);
            }
        }
        int o = ot * 16 + r;
        float bo = bias[o];
        float rs = 0.f, rq = 0.f;
        #pragma unroll
        for (int rg = 0; rg < 4; rg++) {
            int rowl = q * 4 + rg;
            int sp = (d0 + dl) * 224 + (h0 + (rowl >> 3)) * 8 + (rowl & 7);
            float v = fmaxf(acc[rg] + bo, 0.f);
            Ybf[(size_t)(b * SP + sp) * OPAD + o] = f2b(v);
            rs += v; rq += v * v;
        }
        rs += __shfl_xor(rs, 16, 64); rs += __shfl_xor(rs, 32, 64);
        rq += __shfl_xor(rq, 16, 64); rq += __shfl_xor(rq, 32, 64);
        if (l < 16) { atomicAdd(&s_sum[ot * 16 + l], rs); atomicAdd(&s_sq[ot * 16 + l], rq); }
        return;
    }

    const u16* a0p = xs + ((4 + hl + 1) * 10 + wl + 1) * HS + 8 * q;  // dl=0
    const u16* a1p = a0p + 40 * HS;                                   // dl=1

    if (WIDE) {
        // 128 outputs per block: wave owns o-tiles wv and wv+4 (o, o+64)
        v4f acc[2][2];                       // [oti][dl]
        acc[0][0] = (v4f){0.f,0.f,0.f,0.f}; acc[0][1] = (v4f){0.f,0.f,0.f,0.f};
        acc[1][0] = (v4f){0.f,0.f,0.f,0.f}; acc[1][1] = (v4f){0.f,0.f,0.f,0.f};
        #pragma unroll
        for (int t = 0; t < 27; t++) {
            const int koff = ((t / 9) - 1) * 40 + (((t / 3) % 3) - 1) * 10 + (t % 3) - 1;
            const u16* wt  = Wpk + ((size_t)(t * NOT + wv) * NC << 9) + l * 8;
            const u16* wt2 = wt + (size_t)4 * NC * 512;      // ot = wv+4
            #pragma unroll
            for (int ch = 0; ch < NC; ch++) {
                v8s a0 = *(const v8s*)(a0p + koff * HS + ch * 32);
                v8s a1 = *(const v8s*)(a1p + koff * HS + ch * 32);
                v8s b0 = *(const v8s*)(wt + ch * 512);
                v8s b1 = *(const v8s*)(wt2 + ch * 512);
                acc[0][0] = __builtin_amdgcn_mfma_f32_16x16x32_bf16(a0, b0, acc[0][0], 0, 0, 0);
                acc[0][1] = __builtin_amdgcn_mfma_f32_16x16x32_bf16(a1, b0, acc[0][1], 0, 0, 0);
                acc[1][0] = __builtin_amdgcn_mfma_f32_16x16x32_bf16(a0, b1, acc[1][0], 0, 0, 0);
                acc[1][1] = __builtin_amdgcn_mfma_f32_16x16x32_bf16(a1, b1, acc[1][1], 0, 0, 0);
            }
        }
        #pragma unroll
        for (int oti = 0; oti < 2; oti++) {
            int o_base = wv * 16 + oti * 64;
            int oo = o_base + r;
            float bo = bias[oo];
            float rs = 0.f, rq = 0.f;
            #pragma unroll
            for (int s2 = 0; s2 < 2; s2++) {
                v4f A = acc[oti][s2];
                #pragma unroll
                for (int rg = 0; rg < 4; rg++) {
                    int rowl = q * 4 + rg;
                    int sp = (d0 + s2) * 224 + (h0 + (rowl >> 3)) * 8 + (rowl & 7);
                    float v = fmaxf(A[rg] + bo, 0.f);
                    Ybf[(size_t)(b * SP + sp) * OPAD + oo] = f2b(v);
                    rs += v; rq += v * v;
                }
            }
            rs += __shfl_xor(rs, 16, 64); rs += __shfl_xor(rs, 32, 64);
            rq += __shfl_xor(rq, 16, 64); rq += __shfl_xor(rq, 32, 64);
            if (l < 16) { atomicAdd(&s_sum[o_base + l], rs); atomicAdd(&s_sq[o_base + l], rq); }
        }
        return;
    }

    int o_base = blockIdx.y * 64 + wv * 16;
    int o = o_base + r;
    int otg = o_base >> 4;                   // fragment o-tile index

    v4f acc0 = {0.f, 0.f, 0.f, 0.f}, acc1 = {0.f, 0.f, 0.f, 0.f};
    #pragma unroll
    for (int t = 0; t < 27; t++) {
        const int koff = ((t / 9) - 1) * 40 + (((t / 3) % 3) - 1) * 10 + (t % 3) - 1;
        const u16* wt = Wpk + ((size_t)(t * NOT + otg) * NC << 9) + l * 8;
        #pragma unroll
        for (int ch = 0; ch < NC; ch++) {
            v8s a0 = *(const v8s*)(a0p + koff * HS + ch * 32);
            v8s a1 = *(const v8s*)(a1p + koff * HS + ch * 32);
            v8s bf = *(const v8s*)(wt + ch * 512);
            acc0 = __builtin_amdgcn_mfma_f32_16x16x32_bf16(a0, bf, acc0, 0, 0, 0);
            acc1 = __builtin_amdgcn_mfma_f32_16x16x32_bf16(a1, bf, acc1, 0, 0, 0);
        }
    }

    {
        float bo = bias[o];
        float rs = 0.f, rq = 0.f;
        #pragma unroll
        for (int s2 = 0; s2 < 2; s2++) {
            v4f A = s2 ? acc1 : acc0;
            #pragma unroll
            for (int rg = 0; rg < 4; rg++) {
                int rowl = q * 4 + rg;
                int sp = (d0 + s2) * 224 + (h0 + (rowl >> 3)) * 8 + (rowl & 7);
                float v = fmaxf(A[rg] + bo, 0.f);
                Ybf[(size_t)(b * SP + sp) * OPAD + o] = f2b(v);
                rs += v; rq += v * v;
            }
        }
        rs += __shfl_xor(rs, 16, 64); rs += __shfl_xor(rs, 32, 64);
        rq += __shfl_xor(rq, 16, 64); rq += __shfl_xor(rq, 32, 64);
        if (l < 16) { atomicAdd(&s_sum[o_base + l], rs); atomicAdd(&s_sq[o_base + l], rq); }
    }
}

// ---------------- deformable conv (MFMA) -- R21 structure (measured 114.7us) ----
// 2-tap per barrier set; scalar-fmaf sample phase; 32 positions; grid 800.
// R11/R13-R16/R18/R22 (micro-variants), R24 (global-atomic partials: 206MB write
// storm), R25 (position-split: per-block fixed work doubled, +22us) all lost to
// this skeleton: VGPR 56, LDS 33KB, conflicts 2.7M.
__global__ __launch_bounds__(256) __attribute__((amdgpu_waves_per_eu(1, 4)))
void deform_pool(const u16* __restrict__ Ht, const float* __restrict__ OFF,
                 const u16* __restrict__ Wa, const float* __restrict__ db,
                 float* __restrict__ pooledraw, float* __restrict__ sumsq4)
{
    __shared__ float offs_lds[81 * 32];     // [ch][p]
    __shared__ int ig_s[2][32][8][2];       // [tap][p][corner][{idx, g bits}]
    __shared__ u16 Vb[2][32][136];          // [tap][p][c] bf16, row pad +8
    __shared__ float reds[128], redq[128];

    int fid = blockIdx.x;          // [0,800)
    int xcd = fid & 7;
    int local = fid >> 3;          // [0,100)
    if (local >= 98) return;
    int b = xcd >> 1;
    int d = (xcd & 1) * 14 + local / 7;
    int h0 = (local % 7) * 4;

    int t = threadIdx.x;
    if (t < 128) { reds[t] = 0.f; redq[t] = 0.f; }

    int gp = t >> 3, gcr = t & 7;                  // geometry role
    int glh = gp >> 3, gw = gp & 7, gh = h0 + glh;
    int co = t & 15, pg = t >> 4;                  // sample role: c-oct, p-pair
    int l = t & 63, wv = t >> 6;                   // MFMA role
    int q = l >> 4, r = l & 15;

    v4f acc[2][2];                                 // [o-tile][p-tile]
    acc[0][0] = (v4f){0.f,0.f,0.f,0.f}; acc[0][1] = (v4f){0.f,0.f,0.f,0.f};
    acc[1][0] = (v4f){0.f,0.f,0.f,0.f}; acc[1][1] = (v4f){0.f,0.f,0.f,0.f};

    const u16* hb = Ht + (size_t)b * SP * 128;

    // ---- stage offsets for this block's 32 positions (coalesced, once) ----
    for (int i = t; i < 2592; i += 256) {
        int ch = i >> 5, p = i & 31;
        offs_lds[i] = OFF[(size_t)b * 81 * SP + (size_t)ch * SP
                          + d * 224 + (h0 + (p >> 3)) * 8 + (p & 7)];
    }

    auto GEOM = [&](int n, int tap) {
        int kd = n / 9 - 1, kh = (n / 3) % 3 - 1, kw = n % 3 - 1;
        float od  = offs_lds[n * 32 + gp];
        float oh  = offs_lds[(27 + n) * 32 + gp];
        float owv = offs_lds[(54 + n) * 32 + gp];
        float pd = fminf(fmaxf((float)(d + 1 + kd) + od, 0.f), 29.f);
        float ph = fminf(fmaxf((float)(gh + 1 + kh) + oh, 0.f), 29.f);
        float pw = fminf(fmaxf((float)(gw + 1 + kw) + owv, 0.f), 9.f);
        float qd = fminf(floorf(pd), 28.f);
        float qh = fminf(floorf(ph), 28.f);
        float qw = fminf(floorf(pw), 8.f);
        float td = fminf(pd - qd, 1.f);
        float th = fminf(ph - qh, 1.f);
        float tw = fminf(pw - qw, 1.f);
        int iqd = (int)qd - 1, iqh = (int)qh - 1, iqw = (int)qw - 1;
        int i = gcr >> 2, j = (gcr >> 1) & 1, k = gcr & 1;
        int du = iqd + i, hu = iqh + j, wu = iqw + k;
        bool val = (unsigned)du < 28u && (unsigned)hu < 28u && (unsigned)wu < 8u;
        float gg = (i ? td : 1.f - td) * (j ? th : 1.f - th) * (k ? tw : 1.f - tw);
        ig_s[tap][gp][gcr][0] = val ? (du * 224 + hu * 8 + wu) : 0;
        ig_s[tap][gp][gcr][1] = __float_as_int(val ? gg : 0.f);
    };

    auto SAMPLE = [&](int tap) {
        #pragma unroll
        for (int pp = 0; pp < 2; pp++) {
            int p = pg * 2 + pp;
            float va[8] = {0.f,0.f,0.f,0.f,0.f,0.f,0.f,0.f};
            #pragma unroll
            for (int cr = 0; cr < 8; cr++) {
                int2 pr = *(const int2*)&ig_s[tap][p][cr][0];
                float gg = __int_as_float(pr.y);
                uint4 xv = *(const uint4*)(hb + (size_t)pr.x * 128 + co * 8);
                va[0] = fmaf(gg, b2f_lo(xv.x), va[0]);
                va[1] = fmaf(gg, b2f_hi(xv.x), va[1]);
                va[2] = fmaf(gg, b2f_lo(xv.y), va[2]);
                va[3] = fmaf(gg, b2f_hi(xv.y), va[3]);
                va[4] = fmaf(gg, b2f_lo(xv.z), va[4]);
                va[5] = fmaf(gg, b2f_hi(xv.z), va[5]);
                va[6] = fmaf(gg, b2f_lo(xv.w), va[6]);
                va[7] = fmaf(gg, b2f_hi(xv.w), va[7]);
            }
            uint4 pk;
            pk.x = pk2(va[0], va[1]); pk.y = pk2(va[2], va[3]);
            pk.z = pk2(va[4], va[5]); pk.w = pk2(va[6], va[7]);
            *(uint4*)&Vb[tap][p][co * 8] = pk;
        }
    };

    auto MFMA_TAP = [&](int n, int tap) {
        const u16* wn = Wa + (size_t)n * 16384;
        #pragma unroll
        for (int oti = 0; oti < 2; oti++) {
            int ot = wv * 2 + oti;
            #pragma unroll
            for (int kc = 0; kc < 4; kc++) {
                v8s af = *(const v8s*)(wn + ((((ot * 4 + kc) * 4 + q) * 16 + r) * 8));
                v8s bf0 = *(const v8s*)&Vb[tap][r][kc * 32 + q * 8];
                v8s bf1 = *(const v8s*)&Vb[tap][16 + r][kc * 32 + q * 8];
                acc[oti][0] = __builtin_amdgcn_mfma_f32_16x16x32_bf16(af, bf0, acc[oti][0], 0, 0, 0);
                acc[oti][1] = __builtin_amdgcn_mfma_f32_16x16x32_bf16(af, bf1, acc[oti][1], 0, 0, 0);
            }
        }
    };

    for (int it = 0; it < 14; it++) {
        int n0 = it * 2, n1 = n0 + 1;
        bool two = (n1 < 27);                      // uniform across block
        __syncthreads();   // prev MFMA done reading Vb (and offs_lds ready, it=0)
        GEOM(n0, 0);
        if (two) GEOM(n1, 1);
        __syncthreads();
        SAMPLE(0);
        if (two) SAMPLE(1);
        __syncthreads();
        MFMA_TAP(n0, 0);
        if (two) MFMA_TAP(n1, 1);
    }

    // ---- epilogue: bias + relu + pooled sum / sumsq ----
    #pragma unroll
    for (int oti = 0; oti < 2; oti++) {
        #pragma unroll
        for (int rg = 0; rg < 4; rg++) {
            int o = (wv * 2 + oti) * 16 + q * 4 + rg;
            float bo = db[o];
            float v0 = fmaxf(acc[oti][0][rg] + bo, 0.f);
            float v1 = fmaxf(acc[oti][1][rg] + bo, 0.f);
            float s = v0 + v1, qq = v0 * v0 + v1 * v1;
            s += __shfl_xor(s, 1, 64);  qq += __shfl_xor(qq, 1, 64);
            s += __shfl_xor(s, 2, 64);  qq += __shfl_xor(qq, 2, 64);
            s += __shfl_xor(s, 4, 64);  qq += __shfl_xor(qq, 4, 64);
            s += __shfl_xor(s, 8, 64);  qq += __shfl_xor(qq, 8, 64);
            if (r == 0) { atomicAdd(&reds[o], s); atomicAdd(&redq[o], qq); }
        }
    }
    __syncthreads();
    if (t < 128) {
        atomicAdd(&pooledraw[b * 128 + t], reds[t]);
        atomicAdd(&sumsq4[t], redq[t]);
    }
}

// ---------------- tail kernel: BN4+pool+FC+log_softmax (offsets already in d_out) ----
__global__ __launch_bounds__(256) void final_head_emit(const float* __restrict__ pooledraw,
        const float* __restrict__ sumsq4, const float* __restrict__ g4,
        const float* __restrict__ b4, const float* __restrict__ fcw,
        const float* __restrict__ fcb, float* __restrict__ out)
{
    int t = threadIdx.x;
    __shared__ float pooled_s[4][128];
    __shared__ float logits[4][10];
    if (t < 128) {
        float s0 = pooledraw[t], s1 = pooledraw[128 + t];
        float s2 = pooledraw[256 + t], s3 = pooledraw[384 + t];
        float tot = s0 + s1 + s2 + s3;
        float m  = tot * (1.f / NSP);
        float v  = sumsq4[t] * (1.f / NSP) - m * m;
        float sc = g4[t] * rsqrtf(v + EPS);
        float sh = b4[t] - m * sc;
        pooled_s[0][t] = s0 * (1.f / SP) * sc + sh;
        pooled_s[1][t] = s1 * (1.f / SP) * sc + sh;
        pooled_s[2][t] = s2 * (1.f / SP) * sc + sh;
        pooled_s[3][t] = s3 * (1.f / SP) * sc + sh;
    }
    __syncthreads();
    if (t < 40) {
        int b = t / 10, j = t % 10;
        float l = fcb[j];
        for (int c = 0; c < 128; c++) l = fmaf(pooled_s[b][c], fcw[j * 128 + c], l);
        logits[b][j] = l;
    }
    __syncthreads();
    if (t < 4) {
        float mx = -1e30f;
        for (int j = 0; j < 10; j++) mx = fmaxf(mx, logits[t][j]);
        float se = 0.f;
        for (int j = 0; j < 10; j++) se += expf(logits[t][j] - mx);
        float lse = mx + logf(se);
        for (int j = 0; j < 10; j++) out[t * 10 + j] = logits[t][j] - lse;
    }
}

extern "C" void kernel_launch(void* const* d_in, const int* in_sizes, int n_in,
                              void* d_out, int out_size, void* d_ws, size_t ws_size,
                              hipStream_t stream)
{
    (void)in_sizes; (void)n_in; (void)out_size; (void)ws_size;
    const float* x   = (const float*)d_in[0];
    const float* c1w = (const float*)d_in[1];
    const float* c1b = (const float*)d_in[2];
    const float* g1  = (const float*)d_in[3];
    const float* b1  = (const float*)d_in[4];
    const float* c2w = (const float*)d_in[5];
    const float* c2b = (const float*)d_in[6];
    const float* g2  = (const float*)d_in[7];
    const float* b2  = (const float*)d_in[8];
    const float* c3w = (const float*)d_in[9];
    const float* c3b = (const float*)d_in[10];
    const float* g3  = (const float*)d_in[11];
    const float* b3  = (const float*)d_in[12];
    const float* ow  = (const float*)d_in[13];
    const float* ob  = (const float*)d_in[14];
    const float* dw  = (const float*)d_in[15];
    const float* db  = (const float*)d_in[16];
    const float* g4  = (const float*)d_in[17];
    const float* b4  = (const float*)d_in[18];
    const float* fcw = (const float*)d_in[19];
    const float* fcb = (const float*)d_in[20];

    float* ws = (float*)d_ws;
    float* S2 = ws + 64,  *Q2 = ws + 128;
    float* S3 = ws + 192, *Q3 = ws + 320;
    float* PO = ws + 448;            // 4*128
    float* Q4 = ws + 960;            // 128
    float* P1s = ws + 4096;          // 98*32 conv1 partial sums (no zero-init needed)
    float* P1q = ws + 7232;          // 98*32 conv1 partial sumsq
    u16* y1bf = (u16*)(ws + 16384);        // NSP*32
    u16* y2bf = y1bf + 802816;             // NSP*64
    u16* y3bf = y2bf + 1605632;            // NSP*128
    u16* x3bf = y3bf + 3211264;
    u16* wpk2 = x3bf + 3211264;            // 27*64*32
    u16* wpk3 = wpk2 + 55296;              // 27*128*64
    u16* wpko = wpk3 + 221184;             // 27*128*128 (o>=81 zero)
    u16* dwa  = wpko + 442368;             // 27*128*128 A-frag layout bf16

    float* outf = (float*)d_out;
    float* offp = outf + 40;               // offsets written DIRECTLY to d_out

    // L1: prepack + ws-zero + conv1 (independent; overlapped in one launch)
    prepack_all<<<4752, 256, 0, stream>>>(c2w, c3w, ow, dw, wpk2, wpk3, wpko, dwa,
                                          ws, x, c1w, c1b, y1bf, P1s, P1q);

    // L2: conv2 (BN1 from conv1 partials), SPLIT2 y=2 -> 1568 blocks (~6/CU)
    conv_mfma<32, 64, false, true, false, true, false, true>
        <<<dim3(784, 2), 256, 0, stream>>>(
        y1bf, wpk2, c2b, y2bf, nullptr, S2, Q2, P1s, P1q, g1, b1);

    // L3: conv3 (BN2 from atomics), non-WIDE y=2 -> 1568 blocks (~6/CU)
    conv_mfma<64, 128, false, true, false, false, false, false>
        <<<dim3(784, 2), 256, 0, stream>>>(
        y2bf, wpk3, c3b, y3bf, nullptr, S3, Q3, S2, Q2, g2, b2);

    // L4: offsets conv (BN3 applied in staging, reads y3bf) + bn_bf tail blocks
    //     (write x3bf for deform) -- LDS-limited at 43.5KB, unchanged
    conv_mfma<128, 128, true, true, false, false, true, false>
        <<<2352, 256, 0, stream>>>(
        y3bf, wpko, ob, x3bf, offp, nullptr, nullptr, S3, Q3, g3, b3);

    // L5: deform (R21 structure, grid 800)
    deform_pool<<<800, 256, 0, stream>>>(x3bf, offp, dwa, db, PO, Q4);

    // L6: head
    final_head_emit<<<1, 256, 0, stream>>>(PO, Q4, g4, b4, fcw, fcb, outf);
}

// Round 12
// 338.538 us; speedup vs baseline: 1.9827x; 1.0753x over previous
//
#include <hip/hip_runtime.h>
#include <hip/hip_bf16.h>
#include <math.h>

#define BB 4
#define SP 6272      // 28*28*8 spatial per batch
#define NSP 25088    // BB*SP
#define EPS 1e-5f

typedef unsigned short u16;
typedef __attribute__((ext_vector_type(8))) short v8s;   // 8 bf16 (4 VGPRs)
typedef __attribute__((ext_vector_type(4))) float v4f;   // MFMA accumulator

__device__ __forceinline__ u16 f2b(float f) {            // fp32 -> bf16 RNE
    unsigned u = __float_as_uint(f);
    return (u16)((u + 0x7fffu + ((u >> 16) & 1u)) >> 16);
}
__device__ __forceinline__ float b2f(u16 s) {
    return __uint_as_float(((unsigned)s) << 16);
}
__device__ __forceinline__ float b2f_lo(unsigned x) { return __uint_as_float(x << 16); }
__device__ __forceinline__ float b2f_hi(unsigned x) { return __uint_as_float(x & 0xffff0000u); }
__device__ __forceinline__ unsigned pk2(float a, float b) {   // v_cvt_pk_bf16_f32
    __hip_bfloat162 h = __float22bfloat162_rn(make_float2(a, b));
    unsigned u;
    __builtin_memcpy(&u, &h, 4);
    return u;
}

// ---------------- conv1: 1->32, shuffle form; stats fused into epilogue ----------------
__global__ __launch_bounds__(256) __attribute__((amdgpu_waves_per_eu(1, 4)))
void conv1_shfl(const float* __restrict__ X, const float* __restrict__ Wt,
                const float* __restrict__ bias, u16* __restrict__ Ybf,
                float* __restrict__ s_sum, float* __restrict__ s_sq)
{
    const int OT = 16;
    __shared__ float red[4][32];
    int xblk = blockIdx.x;                       // [0,104): 13 contiguous blocks per XCD
    int sblk = (xblk & 7) * 13 + (xblk >> 3);
    if (sblk >= 98) return;
    int t = threadIdx.x;
    int s = sblk * 256 + t;
    int b = s / SP;
    int sp = s - b * SP;
    int d = sp / 224;
    int r = sp - d * 224;
    int h = r >> 3;
    int w = r & 7;
    int o0 = blockIdx.y * OT;

    float mdh[9]; int odh[9];
    #pragma unroll
    for (int i = 0; i < 3; i++) {
        int dd = d + i - 1;
        float md = ((unsigned)dd < 28u) ? 1.f : 0.f;
        int ddc = min(max(dd, 0), 27);
        #pragma unroll
        for (int j = 0; j < 3; j++) {
            int hh = h + j - 1;
            float mh = ((unsigned)hh < 28u) ? 1.f : 0.f;
            int hhc = min(max(hh, 0), 27);
            mdh[i * 3 + j] = md * mh;
            odh[i * 3 + j] = ddc * 224 + hhc * 8 + w;
        }
    }
    float mw0 = (w > 0) ? 1.f : 0.f;
    float mw2 = (w < 7) ? 1.f : 0.f;

    float acc[OT];
    #pragma unroll
    for (int oo = 0; oo < OT; oo++) acc[oo] = bias[o0 + oo];

    const float* xc = X + (size_t)b * SP;
    #pragma unroll
    for (int t9 = 0; t9 < 9; t9++) {
        float x0 = xc[odh[t9]];
        float m = mdh[t9];
        float xm = __shfl_up(x0, 1, 64) * (m * mw0);
        float xz = x0 * m;
        float xp = __shfl_down(x0, 1, 64) * (m * mw2);
        #pragma unroll
        for (int oo = 0; oo < OT; oo++) {
            const float* wp = Wt + (size_t)(o0 + oo) * 27 + t9 * 3;
            acc[oo] = fmaf(xm, wp[0], acc[oo]);
            acc[oo] = fmaf(xz, wp[1], acc[oo]);
            acc[oo] = fmaf(xp, wp[2], acc[oo]);
        }
    }
    float sv[OT];
    #pragma unroll
    for (int oo = 0; oo < OT; oo++) sv[oo] = fmaxf(acc[oo], 0.f);

    unsigned pk[8];
    #pragma unroll
    for (int j = 0; j < 8; j++) pk[j] = pk2(sv[2 * j], sv[2 * j + 1]);
    u16* row = Ybf + (size_t)(b * SP + sp) * 32 + o0;
    *(uint4*)(row)     = make_uint4(pk[0], pk[1], pk[2], pk[3]);
    *(uint4*)(row + 8) = make_uint4(pk[4], pk[5], pk[6], pk[7]);

    // ---- fused stats: wave butterfly per channel, then 32 atomics/block ----
    int l = t & 63, wvv = t >> 6;
    #pragma unroll
    for (int oo = 0; oo < OT; oo++) {
        float ss = sv[oo], qv = ss * ss;
        #pragma unroll
        for (int m = 1; m < 64; m <<= 1) {
            ss += __shfl_xor(ss, m, 64);
            qv += __shfl_xor(qv, m, 64);
        }
        if (l == 0) { red[wvv][oo] = ss; red[wvv][16 + oo] = qv; }
    }
    __syncthreads();
    if (t < 32) {
        float tot = red[0][t] + red[1][t] + red[2][t] + red[3][t];
        if (t < 16) atomicAdd(&s_sum[o0 + t], tot);
        else        atomicAdd(&s_sq[o0 + t - 16], tot);
    }
}

// ---------------- merged weight prepack + workspace zeroing ----------------
// Weights for the MFMA convs are packed in FRAGMENT layout [t][ot][ch][q][r][j]
// (lane l = q*16+r reads 16B at base + l*8): one coalesced 1KB L2 request per
// B-load instead of 16/32/64 scattered line requests (R20 fix: -120us).
__global__ __launch_bounds__(256) void prepack_all(const float* __restrict__ c2w,
        const float* __restrict__ c3w, const float* __restrict__ ow,
        const float* __restrict__ dw, u16* __restrict__ wpk2,
        u16* __restrict__ wpk3, u16* __restrict__ wpko, u16* __restrict__ dwa,
        float* __restrict__ ws0)
{
    int bx = blockIdx.x;
    if (bx >= 4536) {                            // 8 blocks: zero ws[0..2048)
        int i = (bx - 4536) * 256 + threadIdx.x;
        if (i < 2048) ws0[i] = 0.f;
        return;
    }
    int idx = bx * 256 + threadIdx.x;
    if (idx < 55296) {
        // wpk2[t][ot:4][q][r][j]  (CIN=32, NC=1)
        int i = idx;
        int j = i & 7, r = (i >> 3) & 15, q = (i >> 7) & 3;
        int ot = (i >> 9) & 3, t = i >> 11;
        int o = ot * 16 + r, c = q * 8 + j;
        wpk2[i] = f2b(c2w[((size_t)o * 32 + c) * 27 + t]);
    } else if (idx < 276480) {
        // wpk3[t][ot:8][ch:2][q][r][j]  (CIN=64)
        int i = idx - 55296;
        int j = i & 7, r = (i >> 3) & 15, q = (i >> 7) & 3;
        int ch = (i >> 9) & 1, ot = (i >> 10) & 7, t = i >> 13;
        int o = ot * 16 + r, c = ch * 32 + q * 8 + j;
        wpk3[i] = f2b(c3w[((size_t)o * 64 + c) * 27 + t]);
    } else if (idx < 718848) {
        // wpko[t][ot:8][ch:4][q][r][j]  (CIN=128, o>=81 zero)
        int i = idx - 276480;
        int j = i & 7, r = (i >> 3) & 15, q = (i >> 7) & 3;
        int ch = (i >> 9) & 3, ot = (i >> 11) & 7, t = i >> 14;
        int o = ot * 16 + r, c = ch * 32 + q * 8 + j;
        wpko[i] = f2b((o < 81) ? ow[((size_t)o * 128 + c) * 27 + t] : 0.f);
    } else {
        int i = idx - 718848;   // dwa[n][ot][kc][q][r][j]
        int j = i & 7, r = (i >> 3) & 15, q = (i >> 7) & 3;
        int kc = (i >> 9) & 3, ot = (i >> 11) & 7, n = i >> 14;
        int o = ot * 16 + r, c = kc * 32 + q * 8 + j;
        dwa[i] = f2b(dw[((size_t)o * 128 + c) * 27 + n]);
    }
}

// ---------------- MFMA implicit-GEMM conv 3x3x3 (CIN>=32, bf16) ----------------
// BNIN: apply per-channel affine (from stats) during LDS staging.
// WIDE: 128 outputs in ONE block; wave owns o-tiles wv, wv+4 x 2 d-slices.
// OFFOUT: merged offsets conv; wave = (d-slice, o-tile trio), o in [0,96).
// Weights read in fragment layout (see prepack_all).
template<int CIN, int OPAD, bool OFFOUT, bool BNIN, bool WIDE>
__global__ __launch_bounds__(256) __attribute__((amdgpu_waves_per_eu(1, 4)))
void conv_mfma(const u16* __restrict__ X, const u16* __restrict__ Wpk,
               const float* __restrict__ bias, u16* __restrict__ Ybf,
               float* __restrict__ offs, float* __restrict__ s_sum,
               float* __restrict__ s_sq, const float* __restrict__ in_sum,
               const float* __restrict__ in_sq, const float* __restrict__ in_g,
               const float* __restrict__ in_b)
{
    const int HS = CIN + 8;                 // LDS stride per position (bf16 units)
    const int NOT = OPAD / 16;              // o-tiles in fragment layout
    const int NC = CIN / 32;                // c-chunks in fragment layout
    __shared__ u16 xs[160 * HS];            // [dz 0..3][hz 0..3][wz 0..9][c]
    __shared__ float scin[BNIN ? CIN : 1], shin[BNIN ? CIN : 1];

    int tid = threadIdx.x;
    int fid = blockIdx.x;                   // [0,784) = 8 XCDs x 98
    int g = (fid & 7) * 98 + (fid >> 3);
    int b = g / 196;
    int rem = g - b * 196;
    int d0 = (rem / 14) * 2, h0 = (rem % 14) * 2;

    if (BNIN) {
        if (tid < CIN) {
            float m = in_sum[tid] * (1.f / NSP);
            float v = in_sq[tid] * (1.f / NSP) - m * m;
            float sc = in_g[tid] * rsqrtf(v + EPS);
            scin[tid] = sc;
            shin[tid] = in_b[tid] - m * sc;
        }
        __syncthreads();
    }

    const int NCH = CIN / 8;
    for (int idx = tid; idx < 160 * NCH; idx += 256) {
        int pos = idx / NCH, ch = idx - pos * NCH;
        int dz = pos / 40, r2 = pos - dz * 40;
        int hz = r2 / 10, wz = r2 - hz * 10;
        int dd = d0 + dz - 1, hh = h0 + hz - 1, ww = wz - 1;
        uint4 val = make_uint4(0, 0, 0, 0);
        if ((unsigned)dd < 28u && (unsigned)hh < 28u && (unsigned)ww < 8u) {
            val = *(const uint4*)(X + ((size_t)(b * SP + dd * 224 + hh * 8 + ww) * CIN + ch * 8));
            if (BNIN) {
                int cb = ch * 8;
                float f0 = b2f_lo(val.x) * scin[cb]     + shin[cb];
                float f1 = b2f_hi(val.x) * scin[cb + 1] + shin[cb + 1];
                float f2 = b2f_lo(val.y) * scin[cb + 2] + shin[cb + 2];
                float f3 = b2f_hi(val.y) * scin[cb + 3] + shin[cb + 3];
                float f4 = b2f_lo(val.z) * scin[cb + 4] + shin[cb + 4];
                float f5 = b2f_hi(val.z) * scin[cb + 5] + shin[cb + 5];
                float f6 = b2f_lo(val.w) * scin[cb + 6] + shin[cb + 6];
                float f7 = b2f_hi(val.w) * scin[cb + 7] + shin[cb + 7];
                val.x = pk2(f0, f1); val.y = pk2(f2, f3);
                val.z = pk2(f4, f5); val.w = pk2(f6, f7);
            }
        }
        *(uint4*)(xs + pos * HS + ch * 8) = val;
    }
    __syncthreads();

    int l = tid & 63, wv = tid >> 6;
    int q = l >> 4, r = l & 15;
    int hl = r >> 3, wl = r & 7;

    if (OFFOUT) {
        // merged offsets conv: wave = (d-slice dl, o-tile trio ot0..ot0+2)
        int dl = wv >> 1;
        int ot0 = (wv & 1) * 3;
        const u16* ap = xs + ((4 + hl + 1) * 10 + wl + 1) * HS + 8 * q + dl * 40 * HS;
        v4f acc[3];
        acc[0] = (v4f){0.f,0.f,0.f,0.f};
        acc[1] = (v4f){0.f,0.f,0.f,0.f};
        acc[2] = (v4f){0.f,0.f,0.f,0.f};
        #pragma unroll
        for (int t = 0; t < 27; t++) {
            const int koff = ((t / 9) - 1) * 40 + (((t / 3) % 3) - 1) * 10 + (t % 3) - 1;
            // fragment base for (t, ot0, ch=0): ((t*NOT+ot0)*NC)*512 + l*8
            const u16* wt = Wpk + ((size_t)(t * NOT + ot0) * NC << 9) + l * 8;
            #pragma unroll
            for (int ch = 0; ch < NC; ch++) {
                v8s a0 = *(const v8s*)(ap + koff * HS + ch * 32);
                v8s b0 = *(const v8s*)(wt + ch * 512);
                v8s b1 = *(const v8s*)(wt + (NC + ch) * 512);
                v8s b2 = *(const v8s*)(wt + (2 * NC + ch) * 512);
                acc[0] = __builtin_amdgcn_mfma_f32_16x16x32_bf16(a0, b0, acc[0], 0, 0, 0);
                acc[1] = __builtin_amdgcn_mfma_f32_16x16x32_bf16(a0, b1, acc[1], 0, 0, 0);
                acc[2] = __builtin_amdgcn_mfma_f32_16x16x32_bf16(a0, b2, acc[2], 0, 0, 0);
            }
        }
        int o0 = ot0 * 16 + r;
        #pragma unroll
        for (int j = 0; j < 3; j++) {
            int o = o0 + 16 * j;
            if (o < 81) {
                float bo = bias[o];
                #pragma unroll
                for (int rg = 0; rg < 4; rg++) {
                    int rowl = q * 4 + rg;
                    int sp = (d0 + dl) * 224 + (h0 + (rowl >> 3)) * 8 + (rowl & 7);
                    offs[((size_t)(b * 81 + o)) * SP + sp] = acc[j][rg] + bo;
                }
            }
        }
        return;
    }

    const u16* a0p = xs + ((4 + hl + 1) * 10 + wl + 1) * HS + 8 * q;  // dl=0
    const u16* a1p = a0p + 40 * HS;                                   // dl=1

    if (WIDE) {
        // 128 outputs per block: wave owns o-tiles wv and wv+4 (o, o+64)
        v4f acc[2][2];                       // [oti][dl]
        acc[0][0] = (v4f){0.f,0.f,0.f,0.f}; acc[0][1] = (v4f){0.f,0.f,0.f,0.f};
        acc[1][0] = (v4f){0.f,0.f,0.f,0.f}; acc[1][1] = (v4f){0.f,0.f,0.f,0.f};
        #pragma unroll
        for (int t = 0; t < 27; t++) {
            const int koff = ((t / 9) - 1) * 40 + (((t / 3) % 3) - 1) * 10 + (t % 3) - 1;
            const u16* wt  = Wpk + ((size_t)(t * NOT + wv) * NC << 9) + l * 8;
            const u16* wt2 = wt + (size_t)4 * NC * 512;      // ot = wv+4
            #pragma unroll
            for (int ch = 0; ch < NC; ch++) {
                v8s a0 = *(const v8s*)(a0p + koff * HS + ch * 32);
                v8s a1 = *(const v8s*)(a1p + koff * HS + ch * 32);
                v8s b0 = *(const v8s*)(wt + ch * 512);
                v8s b1 = *(const v8s*)(wt2 + ch * 512);
                acc[0][0] = __builtin_amdgcn_mfma_f32_16x16x32_bf16(a0, b0, acc[0][0], 0, 0, 0);
                acc[0][1] = __builtin_amdgcn_mfma_f32_16x16x32_bf16(a1, b0, acc[0][1], 0, 0, 0);
                acc[1][0] = __builtin_amdgcn_mfma_f32_16x16x32_bf16(a0, b1, acc[1][0], 0, 0, 0);
                acc[1][1] = __builtin_amdgcn_mfma_f32_16x16x32_bf16(a1, b1, acc[1][1], 0, 0, 0);
            }
        }
        #pragma unroll
        for (int oti = 0; oti < 2; oti++) {
            int o_base = wv * 16 + oti * 64;
            int oo = o_base + r;
            float bo = bias[oo];
            float rs = 0.f, rq = 0.f;
            #pragma unroll
            for (int s2 = 0; s2 < 2; s2++) {
                v4f A = acc[oti][s2];
                #pragma unroll
                for (int rg = 0; rg < 4; rg++) {
                    int rowl = q * 4 + rg;
                    int sp = (d0 + s2) * 224 + (h0 + (rowl >> 3)) * 8 + (rowl & 7);
                    float v = fmaxf(A[rg] + bo, 0.f);
                    Ybf[(size_t)(b * SP + sp) * OPAD + oo] = f2b(v);
                    rs += v; rq += v * v;
                }
            }
            rs += __shfl_xor(rs, 16, 64); rs += __shfl_xor(rs, 32, 64);
            rq += __shfl_xor(rq, 16, 64); rq += __shfl_xor(rq, 32, 64);
            if (l < 16) { atomicAdd(&s_sum[o_base + l], rs); atomicAdd(&s_sq[o_base + l], rq); }
        }
        return;
    }

    int o_base = blockIdx.y * 64 + wv * 16;
    int o = o_base + r;
    int otg = o_base >> 4;                   // fragment o-tile index

    v4f acc0 = {0.f, 0.f, 0.f, 0.f}, acc1 = {0.f, 0.f, 0.f, 0.f};
    #pragma unroll
    for (int t = 0; t < 27; t++) {
        const int koff = ((t / 9) - 1) * 40 + (((t / 3) % 3) - 1) * 10 + (t % 3) - 1;
        const u16* wt = Wpk + ((size_t)(t * NOT + otg) * NC << 9) + l * 8;
        #pragma unroll
        for (int ch = 0; ch < NC; ch++) {
            v8s a0 = *(const v8s*)(a0p + koff * HS + ch * 32);
            v8s a1 = *(const v8s*)(a1p + koff * HS + ch * 32);
            v8s bf = *(const v8s*)(wt + ch * 512);
            acc0 = __builtin_amdgcn_mfma_f32_16x16x32_bf16(a0, bf, acc0, 0, 0, 0);
            acc1 = __builtin_amdgcn_mfma_f32_16x16x32_bf16(a1, bf, acc1, 0, 0, 0);
        }
    }

    {
        float bo = bias[o];
        float rs = 0.f, rq = 0.f;
        #pragma unroll
        for (int s2 = 0; s2 < 2; s2++) {
            v4f A = s2 ? acc1 : acc0;
            #pragma unroll
            for (int rg = 0; rg < 4; rg++) {
                int rowl = q * 4 + rg;
                int sp = (d0 + s2) * 224 + (h0 + (rowl >> 3)) * 8 + (rowl & 7);
                float v = fmaxf(A[rg] + bo, 0.f);
                Ybf[(size_t)(b * SP + sp) * OPAD + o] = f2b(v);
                rs += v; rq += v * v;
            }
        }
        rs += __shfl_xor(rs, 16, 64); rs += __shfl_xor(rs, 32, 64);
        rq += __shfl_xor(rq, 16, 64); rq += __shfl_xor(rq, 32, 64);
        if (l < 16) { atomicAdd(&s_sum[o_base + l], rs); atomicAdd(&s_sq[o_base + l], rq); }
    }
}

// ---------------- BN apply on channel-minor bf16, vectorized uint4/lane ----------------
template<int C>
__global__ __launch_bounds__(256) void bn_bf(const u16* __restrict__ Y,
        const float* __restrict__ s_sum, const float* __restrict__ s_sq,
        const float* __restrict__ g, const float* __restrict__ bb,
        u16* __restrict__ Xo)
{
    __shared__ float sc_s[C], sh_s[C];
    int t = threadIdx.x;
    if (t < C) {
        float m  = s_sum[t] * (1.f / NSP);
        float v  = s_sq[t] * (1.f / NSP) - m * m;
        float sc = g[t] * rsqrtf(v + EPS);
        sc_s[t] = sc;
        sh_s[t] = bb[t] - m * sc;
    }
    __syncthreads();
    int idx = blockIdx.x * 256 + t;              // uint4 index, [0, NSP*C/8)
    uint4 v = ((const uint4*)Y)[idx];
    int cb = (idx & (C / 8 - 1)) * 8;
    float f0 = b2f_lo(v.x) * sc_s[cb]     + sh_s[cb];
    float f1 = b2f_hi(v.x) * sc_s[cb + 1] + sh_s[cb + 1];
    float f2 = b2f_lo(v.y) * sc_s[cb + 2] + sh_s[cb + 2];
    float f3 = b2f_hi(v.y) * sc_s[cb + 3] + sh_s[cb + 3];
    float f4 = b2f_lo(v.z) * sc_s[cb + 4] + sh_s[cb + 4];
    float f5 = b2f_hi(v.z) * sc_s[cb + 5] + sh_s[cb + 5];
    float f6 = b2f_lo(v.w) * sc_s[cb + 6] + sh_s[cb + 6];
    float f7 = b2f_hi(v.w) * sc_s[cb + 7] + sh_s[cb + 7];
    uint4 pk;
    pk.x = pk2(f0, f1); pk.y = pk2(f2, f3);
    pk.z = pk2(f4, f5); pk.w = pk2(f6, f7);
    ((uint4*)Xo)[idx] = pk;
}

// ---------------- deformable conv (MFMA) -- R21: 2-tap iteration ----------------
// R12 phase structure preserved exactly per tap; two taps per barrier set.
// Best measured deform: 114.7us (VGPR 56, LDS 33KB, conflicts 2.7M).
// All variants lost to this: R11/R13-R16/R18 (micro), R22 (pk-FMA rewrite),
// R24 (global-atomic tap-split: 206MB write storm), R25 (position-split),
// R26 (conv-side changes; deform untouched).
__global__ __launch_bounds__(256) __attribute__((amdgpu_waves_per_eu(1, 4)))
void deform_pool(const u16* __restrict__ Ht, const float* __restrict__ OFF,
                 const u16* __restrict__ Wa, const float* __restrict__ db,
                 float* __restrict__ pooledraw, float* __restrict__ sumsq4)
{
    __shared__ float offs_lds[81 * 32];     // [ch][p]
    __shared__ int ig_s[2][32][8][2];       // [tap][p][corner][{idx, g bits}]
    __shared__ u16 Vb[2][32][136];          // [tap][p][c] bf16, row pad +8
    __shared__ float reds[128], redq[128];

    int fid = blockIdx.x;          // [0,800)
    int xcd = fid & 7;
    int local = fid >> 3;          // [0,100)
    if (local >= 98) return;
    int b = xcd >> 1;
    int d = (xcd & 1) * 14 + local / 7;
    int h0 = (local % 7) * 4;

    int t = threadIdx.x;
    if (t < 128) { reds[t] = 0.f; redq[t] = 0.f; }

    int gp = t >> 3, gcr = t & 7;                  // geometry role
    int glh = gp >> 3, gw = gp & 7, gh = h0 + glh;
    int co = t & 15, pg = t >> 4;                  // sample role: c-oct, p-pair
    int l = t & 63, wv = t >> 6;                   // MFMA role
    int q = l >> 4, r = l & 15;

    v4f acc[2][2];                                 // [o-tile][p-tile]
    acc[0][0] = (v4f){0.f,0.f,0.f,0.f}; acc[0][1] = (v4f){0.f,0.f,0.f,0.f};
    acc[1][0] = (v4f){0.f,0.f,0.f,0.f}; acc[1][1] = (v4f){0.f,0.f,0.f,0.f};

    const u16* hb = Ht + (size_t)b * SP * 128;

    // ---- stage offsets for this block's 32 positions (coalesced, once) ----
    for (int i = t; i < 2592; i += 256) {
        int ch = i >> 5, p = i & 31;
        offs_lds[i] = OFF[(size_t)b * 81 * SP + (size_t)ch * SP
                          + d * 224 + (h0 + (p >> 3)) * 8 + (p & 7)];
    }

    auto GEOM = [&](int n, int tap) {
        int kd = n / 9 - 1, kh = (n / 3) % 3 - 1, kw = n % 3 - 1;
        float od  = offs_lds[n * 32 + gp];
        float oh  = offs_lds[(27 + n) * 32 + gp];
        float owv = offs_lds[(54 + n) * 32 + gp];
        float pd = fminf(fmaxf((float)(d + 1 + kd) + od, 0.f), 29.f);
        float ph = fminf(fmaxf((float)(gh + 1 + kh) + oh, 0.f), 29.f);
        float pw = fminf(fmaxf((float)(gw + 1 + kw) + owv, 0.f), 9.f);
        float qd = fminf(floorf(pd), 28.f);
        float qh = fminf(floorf(ph), 28.f);
        float qw = fminf(floorf(pw), 8.f);
        float td = fminf(pd - qd, 1.f);
        float th = fminf(ph - qh, 1.f);
        float tw = fminf(pw - qw, 1.f);
        int iqd = (int)qd - 1, iqh = (int)qh - 1, iqw = (int)qw - 1;
        int i = gcr >> 2, j = (gcr >> 1) & 1, k = gcr & 1;
        int du = iqd + i, hu = iqh + j, wu = iqw + k;
        bool val = (unsigned)du < 28u && (unsigned)hu < 28u && (unsigned)wu < 8u;
        float gg = (i ? td : 1.f - td) * (j ? th : 1.f - th) * (k ? tw : 1.f - tw);
        ig_s[tap][gp][gcr][0] = val ? (du * 224 + hu * 8 + wu) : 0;
        ig_s[tap][gp][gcr][1] = __float_as_int(val ? gg : 0.f);
    };

    auto SAMPLE = [&](int tap) {
        #pragma unroll
        for (int pp = 0; pp < 2; pp++) {
            int p = pg * 2 + pp;
            float va[8] = {0.f,0.f,0.f,0.f,0.f,0.f,0.f,0.f};
            #pragma unroll
            for (int cr = 0; cr < 8; cr++) {
                int2 pr = *(const int2*)&ig_s[tap][p][cr][0];
                float gg = __int_as_float(pr.y);
                uint4 xv = *(const uint4*)(hb + (size_t)pr.x * 128 + co * 8);
                va[0] = fmaf(gg, b2f_lo(xv.x), va[0]);
                va[1] = fmaf(gg, b2f_hi(xv.x), va[1]);
                va[2] = fmaf(gg, b2f_lo(xv.y), va[2]);
                va[3] = fmaf(gg, b2f_hi(xv.y), va[3]);
                va[4] = fmaf(gg, b2f_lo(xv.z), va[4]);
                va[5] = fmaf(gg, b2f_hi(xv.z), va[5]);
                va[6] = fmaf(gg, b2f_lo(xv.w), va[6]);
                va[7] = fmaf(gg, b2f_hi(xv.w), va[7]);
            }
            uint4 pk;
            pk.x = pk2(va[0], va[1]); pk.y = pk2(va[2], va[3]);
            pk.z = pk2(va[4], va[5]); pk.w = pk2(va[6], va[7]);
            *(uint4*)&Vb[tap][p][co * 8] = pk;
        }
    };

    auto MFMA_TAP = [&](int n, int tap) {
        const u16* wn = Wa + (size_t)n * 16384;
        #pragma unroll
        for (int oti = 0; oti < 2; oti++) {
            int ot = wv * 2 + oti;
            #pragma unroll
            for (int kc = 0; kc < 4; kc++) {
                v8s af = *(const v8s*)(wn + ((((ot * 4 + kc) * 4 + q) * 16 + r) * 8));
                v8s bf0 = *(const v8s*)&Vb[tap][r][kc * 32 + q * 8];
                v8s bf1 = *(const v8s*)&Vb[tap][16 + r][kc * 32 + q * 8];
                acc[oti][0] = __builtin_amdgcn_mfma_f32_16x16x32_bf16(af, bf0, acc[oti][0], 0, 0, 0);
                acc[oti][1] = __builtin_amdgcn_mfma_f32_16x16x32_bf16(af, bf1, acc[oti][1], 0, 0, 0);
            }
        }
    };

    for (int it = 0; it < 14; it++) {
        int n0 = it * 2, n1 = n0 + 1;
        bool two = (n1 < 27);                      // uniform across block
        __syncthreads();   // prev MFMA done reading Vb (and offs_lds ready, it=0)
        GEOM(n0, 0);
        if (two) GEOM(n1, 1);
        __syncthreads();
        SAMPLE(0);
        if (two) SAMPLE(1);
        __syncthreads();
        MFMA_TAP(n0, 0);
        if (two) MFMA_TAP(n1, 1);
    }

    // ---- epilogue: bias + relu + pooled sum / sumsq ----
    #pragma unroll
    for (int oti = 0; oti < 2; oti++) {
        #pragma unroll
        for (int rg = 0; rg < 4; rg++) {
            int o = (wv * 2 + oti) * 16 + q * 4 + rg;
            float bo = db[o];
            float v0 = fmaxf(acc[oti][0][rg] + bo, 0.f);
            float v1 = fmaxf(acc[oti][1][rg] + bo, 0.f);
            float s = v0 + v1, qq = v0 * v0 + v1 * v1;
            s += __shfl_xor(s, 1, 64);  qq += __shfl_xor(qq, 1, 64);
            s += __shfl_xor(s, 2, 64);  qq += __shfl_xor(qq, 2, 64);
            s += __shfl_xor(s, 4, 64);  qq += __shfl_xor(qq, 4, 64);
            s += __shfl_xor(s, 8, 64);  qq += __shfl_xor(qq, 8, 64);
            if (r == 0) { atomicAdd(&reds[o], s); atomicAdd(&redq[o], qq); }
        }
    }
    __syncthreads();
    if (t < 128) {
        atomicAdd(&pooledraw[b * 128 + t], reds[t]);
        atomicAdd(&sumsq4[t], redq[t]);
    }
}

// ---------------- tail kernel: BN4+pool+FC+log_softmax (offsets already in d_out) ----
__global__ __launch_bounds__(256) void final_head_emit(const float* __restrict__ pooledraw,
        const float* __restrict__ sumsq4, const float* __restrict__ g4,
        const float* __restrict__ b4, const float* __restrict__ fcw,
        const float* __restrict__ fcb, float* __restrict__ out)
{
    int t = threadIdx.x;
    __shared__ float pooled_s[4][128];
    __shared__ float logits[4][10];
    if (t < 128) {
        float s0 = pooledraw[t], s1 = pooledraw[128 + t];
        float s2 = pooledraw[256 + t], s3 = pooledraw[384 + t];
        float tot = s0 + s1 + s2 + s3;
        float m  = tot * (1.f / NSP);
        float v  = sumsq4[t] * (1.f / NSP) - m * m;
        float sc = g4[t] * rsqrtf(v + EPS);
        float sh = b4[t] - m * sc;
        pooled_s[0][t] = s0 * (1.f / SP) * sc + sh;
        pooled_s[1][t] = s1 * (1.f / SP) * sc + sh;
        pooled_s[2][t] = s2 * (1.f / SP) * sc + sh;
        pooled_s[3][t] = s3 * (1.f / SP) * sc + sh;
    }
    __syncthreads();
    if (t < 40) {
        int b = t / 10, j = t % 10;
        float l = fcb[j];
        for (int c = 0; c < 128; c++) l = fmaf(pooled_s[b][c], fcw[j * 128 + c], l);
        logits[b][j] = l;
    }
    __syncthreads();
    if (t < 4) {
        float mx = -1e30f;
        for (int j = 0; j < 10; j++) mx = fmaxf(mx, logits[t][j]);
        float se = 0.f;
        for (int j = 0; j < 10; j++) se += expf(logits[t][j] - mx);
        float lse = mx + logf(se);
        for (int j = 0; j < 10; j++) out[t * 10 + j] = logits[t][j] - lse;
    }
}

extern "C" void kernel_launch(void* const* d_in, const int* in_sizes, int n_in,
                              void* d_out, int out_size, void* d_ws, size_t ws_size,
                              hipStream_t stream)
{
    (void)in_sizes; (void)n_in; (void)out_size; (void)ws_size;
    const float* x   = (const float*)d_in[0];
    const float* c1w = (const float*)d_in[1];
    const float* c1b = (const float*)d_in[2];
    const float* g1  = (const float*)d_in[3];
    const float* b1  = (const float*)d_in[4];
    const float* c2w = (const float*)d_in[5];
    const float* c2b = (const float*)d_in[6];
    const float* g2  = (const float*)d_in[7];
    const float* b2  = (const float*)d_in[8];
    const float* c3w = (const float*)d_in[9];
    const float* c3b = (const float*)d_in[10];
    const float* g3  = (const float*)d_in[11];
    const float* b3  = (const float*)d_in[12];
    const float* ow  = (const float*)d_in[13];
    const float* ob  = (const float*)d_in[14];
    const float* dw  = (const float*)d_in[15];
    const float* db  = (const float*)d_in[16];
    const float* g4  = (const float*)d_in[17];
    const float* b4  = (const float*)d_in[18];
    const float* fcw = (const float*)d_in[19];
    const float* fcb = (const float*)d_in[20];

    float* ws = (float*)d_ws;
    float* S1 = ws + 0,   *Q1 = ws + 32;
    float* S2 = ws + 64,  *Q2 = ws + 128;
    float* S3 = ws + 192, *Q3 = ws + 320;
    float* PO = ws + 448;   // 4*128
    float* Q4 = ws + 960;   // 128
    u16* y1bf = (u16*)(ws + 2048);         // NSP*32
    u16* y2bf = y1bf + 802816;             // NSP*64
    u16* y3bf = y2bf + 1605632;            // NSP*128
    u16* x3bf = y3bf + 3211264;
    u16* wpk2 = x3bf + 3211264;            // 27*64*32
    u16* wpk3 = wpk2 + 55296;              // 27*128*64
    u16* wpko = wpk3 + 221184;             // 27*128*128 (o>=81 zero)
    u16* dwa  = wpko + 442368;             // 27*128*128 A-frag layout bf16

    float* outf = (float*)d_out;
    float* offp = outf + 40;               // offsets written DIRECTLY to d_out

    prepack_all<<<4544, 256, 0, stream>>>(c2w, c3w, ow, dw, wpk2, wpk3, wpko, dwa, ws);

    conv1_shfl<<<dim3(104, 2), 256, 0, stream>>>(x, c1w, c1b, y1bf, S1, Q1);

    conv_mfma<32, 64, false, true, false><<<dim3(784, 1), 256, 0, stream>>>(
        y1bf, wpk2, c2b, y2bf, nullptr, S2, Q2, S1, Q1, g1, b1);

    // conv3: WIDE -- 128 outputs per block, X-tile staged once
    conv_mfma<64, 128, false, true, true><<<dim3(784, 1), 256, 0, stream>>>(
        y2bf, wpk3, c3b, y3bf, nullptr, S3, Q3, S2, Q2, g2, b2);

    bn_bf<128><<<1568, 256, 0, stream>>>(y3bf, S3, Q3, g3, b3, x3bf);

    // offsets conv: merged single-y launch (6 o-tiles x 2 d over 4 waves)
    conv_mfma<128, 128, true, false, false><<<dim3(784, 1), 256, 0, stream>>>(
        x3bf, wpko, ob, nullptr, offp, nullptr, nullptr, nullptr, nullptr, nullptr, nullptr);

    deform_pool<<<800, 256, 0, stream>>>(x3bf, offp, dwa, db, PO, Q4);
    final_head_emit<<<1, 256, 0, stream>>>(PO, Q4, g4, b4, fcw, fcb, outf);
}